// Round 1
// baseline (404.250 us; speedup 1.0000x reference)
//
#include <hip/hip_runtime.h>
#include <math.h>

#define B_ 2
#define U_ 8
#define V_ 512
#define C_ 256
#define H_ 8
#define DK_ 64
#define R_ 256
#define RH_ 32
#define CODE_ 192
#define EPS_ 1e-6f
#define LN_EPS_ 1e-5f
#define GAIN_ 2.5f

// ---------------- workspace layout (floats) ----------------
// MODS: [5][U][256]                          @ 0        (10240)
// XN:   [8192][256]  (reused as H1)          @ 10240    (2097152)
// Q:    [8192][512]  (reused as YN)          @ 2107392  (4194304)
// K:    [8192][512]                          @ 6301696  (4194304)
// V:    [8192][256]                          @ 10496000 (2097152)
// ATT:  [8192][256]                          @ 12593152 (2097152)
// AO:   [8192][256]                          @ 14690304 (2097152)
// total 16787456 floats = 64.03 MB

__device__ inline float waveReduceSum(float v) {
    #pragma unroll
    for (int m = 1; m < 64; m <<= 1) v += __shfl_xor(v, m);
    return v;
}

__device__ inline float gelu_exact(float x) {
    return 0.5f * x * (1.f + erff(x * 0.70710678118654752f));
}

// mods[kind][u][c] = 1 + codes[u] . Wc_kind[:, c]
__global__ void k_mods(const float* __restrict__ codes,
                       const float* __restrict__ Wcq, const float* __restrict__ Wck,
                       const float* __restrict__ Wcv, const float* __restrict__ Wc1,
                       const float* __restrict__ Wc2, float* __restrict__ mods) {
    int u = blockIdx.x, c = threadIdx.x;
    const float* cd = codes + u * CODE_;
    float aq = 0.f, ak = 0.f, av = 0.f, a1 = 0.f, a2 = 0.f;
    for (int j = 0; j < CODE_; ++j) {
        float cj = cd[j];
        aq = fmaf(cj, Wcq[j * C_ + c], aq);
        ak = fmaf(cj, Wck[j * C_ + c], ak);
        av = fmaf(cj, Wcv[j * C_ + c], av);
        a1 = fmaf(cj, Wc1[j * R_ + c], a1);
        a2 = fmaf(cj, Wc2[j * R_ + c], a2);
    }
    mods[(0 * U_ + u) * C_ + c] = 1.f + aq;
    mods[(1 * U_ + u) * C_ + c] = 1.f + ak;
    mods[(2 * U_ + u) * C_ + c] = 1.f + av;
    mods[(3 * U_ + u) * C_ + c] = 1.f + a1;
    mods[(4 * U_ + u) * C_ + c] = 1.f + a2;
}

// LayerNorm over C=256; one row per wave, 4 waves per block.
__global__ void k_ln1(const float* __restrict__ x, const float* __restrict__ g,
                      const float* __restrict__ b, float* __restrict__ xn) {
    int row = blockIdx.x * 4 + (threadIdx.x >> 6);
    int lane = threadIdx.x & 63;
    const float* xr = x + (size_t)row * C_;
    float v0 = xr[lane], v1 = xr[lane + 64], v2 = xr[lane + 128], v3 = xr[lane + 192];
    float s = v0 + v1 + v2 + v3;
    float ss = v0 * v0 + v1 * v1 + v2 * v2 + v3 * v3;
    s = waveReduceSum(s);
    ss = waveReduceSum(ss);
    float mean = s * (1.f / C_);
    float var = ss * (1.f / C_) - mean * mean;
    float rstd = rsqrtf(var + LN_EPS_);
    float* outr = xn + (size_t)row * C_;
    outr[lane]       = (v0 - mean) * rstd * g[lane]       + b[lane];
    outr[lane + 64]  = (v1 - mean) * rstd * g[lane + 64]  + b[lane + 64];
    outr[lane + 128] = (v2 - mean) * rstd * g[lane + 128] + b[lane + 128];
    outr[lane + 192] = (v3 - mean) * rstd * g[lane + 192] + b[lane + 192];
}

// QKV: out[row, col] = sum_c xn[row,c]*mod[c]*W[c,col] (+bv for V phase)
// grid (20 coltiles, 128 rowtiles), 64x64 output tile, 4x4 per thread, K chunks of 32.
__global__ __launch_bounds__(256) void k_qkv(
    const float* __restrict__ xn, const float* __restrict__ mods,
    const float* __restrict__ Wq, const float* __restrict__ Wk,
    const float* __restrict__ Wv, const float* __restrict__ bv,
    float* __restrict__ qo, float* __restrict__ ko, float* __restrict__ vo) {
    __shared__ __align__(16) float xs[32][65];   // [c][r], padded
    __shared__ __align__(16) float wt[32][64];   // [c][col]
    int coltile = blockIdx.x;
    int row0 = blockIdx.y * 64;
    int u = (row0 / V_) % U_;
    int gcol0 = coltile * 64;
    const float* W; int ldw; int wcol0; float* out; int ldo; int phase;
    if (gcol0 < 512)       { phase = 0; W = Wq; ldw = 512; wcol0 = gcol0;        out = qo; ldo = 512; }
    else if (gcol0 < 1024) { phase = 1; W = Wk; ldw = 512; wcol0 = gcol0 - 512;  out = ko; ldo = 512; }
    else                   { phase = 2; W = Wv; ldw = 256; wcol0 = gcol0 - 1024; out = vo; ldo = 256; }
    const float* msel = mods + (phase * U_ + u) * C_;
    int tid = threadIdx.x;
    int a4 = (tid >> 4) * 4;   // row group
    int b4 = (tid & 15) * 4;   // col group
    float acc[4][4] = {};
    int sc = tid & 31, sr = tid >> 5;
    int wcol = tid & 63, wcc = tid >> 6;
    for (int c0 = 0; c0 < C_; c0 += 32) {
        float mval = msel[c0 + sc];
        #pragma unroll
        for (int it = 0; it < 8; ++it) {
            int r = sr + it * 8;
            xs[sc][r] = xn[(size_t)(row0 + r) * C_ + c0 + sc] * mval;
        }
        #pragma unroll
        for (int it = 0; it < 8; ++it) {
            int c = wcc + it * 4;
            wt[c][wcol] = W[(size_t)(c0 + c) * ldw + wcol0 + wcol];
        }
        __syncthreads();
        #pragma unroll
        for (int c = 0; c < 32; ++c) {
            const float4 wv = *(const float4*)&wt[c][b4];
            const float x0 = xs[c][a4 + 0];
            const float x1 = xs[c][a4 + 1];
            const float x2 = xs[c][a4 + 2];
            const float x3 = xs[c][a4 + 3];
            acc[0][0] = fmaf(x0, wv.x, acc[0][0]); acc[0][1] = fmaf(x0, wv.y, acc[0][1]);
            acc[0][2] = fmaf(x0, wv.z, acc[0][2]); acc[0][3] = fmaf(x0, wv.w, acc[0][3]);
            acc[1][0] = fmaf(x1, wv.x, acc[1][0]); acc[1][1] = fmaf(x1, wv.y, acc[1][1]);
            acc[1][2] = fmaf(x1, wv.z, acc[1][2]); acc[1][3] = fmaf(x1, wv.w, acc[1][3]);
            acc[2][0] = fmaf(x2, wv.x, acc[2][0]); acc[2][1] = fmaf(x2, wv.y, acc[2][1]);
            acc[2][2] = fmaf(x2, wv.z, acc[2][2]); acc[2][3] = fmaf(x2, wv.w, acc[2][3]);
            acc[3][0] = fmaf(x3, wv.x, acc[3][0]); acc[3][1] = fmaf(x3, wv.y, acc[3][1]);
            acc[3][2] = fmaf(x3, wv.z, acc[3][2]); acc[3][3] = fmaf(x3, wv.w, acc[3][3]);
        }
        __syncthreads();
    }
    #pragma unroll
    for (int i = 0; i < 4; ++i) {
        int row = row0 + a4 + i;
        #pragma unroll
        for (int j = 0; j < 4; ++j) {
            int col = wcol0 + b4 + j;
            float val = acc[i][j];
            if (phase == 2) val += bv[col];
            out[(size_t)row * ldo + col] = val;
        }
    }
}

// Attention per (b,u,h) with 64-row q tiles. One streaming pass (no max-sub; scores |s|<~6).
// att[r] = a_r * sum_s(a_s e v) / (a_r * sum_s(a_s e) + EPS * sum_s(e))
__global__ __launch_bounds__(256) void k_attn(
    const float* __restrict__ q, const float* __restrict__ k,
    const float* __restrict__ v, const float* __restrict__ aff,
    float* __restrict__ att) {
    __shared__ __align__(16) float Qt[64][68];
    __shared__ __align__(16) float Kt[64][68];
    __shared__ __align__(16) float Vt[64][36];
    __shared__ __align__(16) float Se[64][68];
    __shared__ float As[64];
    int r0 = blockIdx.x * 64;
    int buh = blockIdx.y;
    int h = buh & 7, bu = buh >> 3;
    const float* qb = q + (size_t)bu * V_ * 512 + h * 64;
    const float* kb = k + (size_t)bu * V_ * 512 + h * 64;
    const float* vb = v + (size_t)bu * V_ * 256 + h * 32;
    const float* ab = aff + bu * V_;
    int tid = threadIdx.x;
    {
        int d = tid & 63, rr = tid >> 6;
        #pragma unroll
        for (int it = 0; it < 16; ++it) {
            int r = rr + it * 4;
            Qt[r][d] = qb[(size_t)(r0 + r) * 512 + d];
        }
    }
    int pr = tid >> 2;       // PV row 0..63
    int sub = tid & 3;       // PV col block (8 cols)
    float accv[8] = {};
    float Ar = 0.f, Wr = 0.f;
    int sa4 = (tid >> 4) * 4;  // score rows
    int sb4 = (tid & 15) * 4;  // score cols (s)
    for (int s0 = 0; s0 < V_; s0 += 64) {
        {
            int d = tid & 63, rr = tid >> 6;
            #pragma unroll
            for (int it = 0; it < 16; ++it) {
                int s = rr + it * 4;
                Kt[s][d] = kb[(size_t)(s0 + s) * 512 + d];
            }
            int c = tid & 31, rr2 = tid >> 5;
            #pragma unroll
            for (int it = 0; it < 8; ++it) {
                int s = rr2 + it * 8;
                Vt[s][c] = vb[(size_t)(s0 + s) * 256 + c];
            }
            if (tid < 64) As[tid] = ab[s0 + tid];
        }
        __syncthreads();
        float scr[4][4] = {};
        #pragma unroll
        for (int d = 0; d < 64; d += 4) {
            float4 q0 = *(const float4*)&Qt[sa4 + 0][d];
            float4 q1 = *(const float4*)&Qt[sa4 + 1][d];
            float4 q2 = *(const float4*)&Qt[sa4 + 2][d];
            float4 q3 = *(const float4*)&Qt[sa4 + 3][d];
            float4 k0 = *(const float4*)&Kt[sb4 + 0][d];
            float4 k1 = *(const float4*)&Kt[sb4 + 1][d];
            float4 k2 = *(const float4*)&Kt[sb4 + 2][d];
            float4 k3 = *(const float4*)&Kt[sb4 + 3][d];
            scr[0][0] += q0.x*k0.x + q0.y*k0.y + q0.z*k0.z + q0.w*k0.w;
            scr[0][1] += q0.x*k1.x + q0.y*k1.y + q0.z*k1.z + q0.w*k1.w;
            scr[0][2] += q0.x*k2.x + q0.y*k2.y + q0.z*k2.z + q0.w*k2.w;
            scr[0][3] += q0.x*k3.x + q0.y*k3.y + q0.z*k3.z + q0.w*k3.w;
            scr[1][0] += q1.x*k0.x + q1.y*k0.y + q1.z*k0.z + q1.w*k0.w;
            scr[1][1] += q1.x*k1.x + q1.y*k1.y + q1.z*k1.z + q1.w*k1.w;
            scr[1][2] += q1.x*k2.x + q1.y*k2.y + q1.z*k2.z + q1.w*k2.w;
            scr[1][3] += q1.x*k3.x + q1.y*k3.y + q1.z*k3.z + q1.w*k3.w;
            scr[2][0] += q2.x*k0.x + q2.y*k0.y + q2.z*k0.z + q2.w*k0.w;
            scr[2][1] += q2.x*k1.x + q2.y*k1.y + q2.z*k1.z + q2.w*k1.w;
            scr[2][2] += q2.x*k2.x + q2.y*k2.y + q2.z*k2.z + q2.w*k2.w;
            scr[2][3] += q2.x*k3.x + q2.y*k3.y + q2.z*k3.z + q2.w*k3.w;
            scr[3][0] += q3.x*k0.x + q3.y*k0.y + q3.z*k0.z + q3.w*k0.w;
            scr[3][1] += q3.x*k1.x + q3.y*k1.y + q3.z*k1.z + q3.w*k1.w;
            scr[3][2] += q3.x*k2.x + q3.y*k2.y + q3.z*k2.z + q3.w*k2.w;
            scr[3][3] += q3.x*k3.x + q3.y*k3.y + q3.z*k3.z + q3.w*k3.w;
        }
        #pragma unroll
        for (int i = 0; i < 4; ++i)
            #pragma unroll
            for (int j = 0; j < 4; ++j)
                Se[sa4 + i][sb4 + j] = __expf(scr[i][j]);
        __syncthreads();
        #pragma unroll 4
        for (int s = 0; s < 64; ++s) {
            float e = Se[pr][s];
            float ae = e * As[s];
            Wr += e;
            Ar += ae;
            float4 v0 = *(const float4*)&Vt[s][sub * 8];
            float4 v1 = *(const float4*)&Vt[s][sub * 8 + 4];
            accv[0] = fmaf(ae, v0.x, accv[0]); accv[1] = fmaf(ae, v0.y, accv[1]);
            accv[2] = fmaf(ae, v0.z, accv[2]); accv[3] = fmaf(ae, v0.w, accv[3]);
            accv[4] = fmaf(ae, v1.x, accv[4]); accv[5] = fmaf(ae, v1.y, accv[5]);
            accv[6] = fmaf(ae, v1.z, accv[6]); accv[7] = fmaf(ae, v1.w, accv[7]);
        }
        __syncthreads();
    }
    float ar = ab[r0 + pr];
    float denom = ar * Ar + EPS_ * Wr;
    float scale = ar / denom;
    float* ob = att + ((size_t)bu * V_ + r0 + pr) * 256 + h * 32 + sub * 8;
    #pragma unroll
    for (int j = 0; j < 8; ++j) ob[j] = accv[j] * scale;
}

// gated residual + LayerNorm2: ao = (1-a)x + a*GAIN*att; yn = LN(ao)*g2 + b2
__global__ void k_gate_ln2(const float* __restrict__ x, const float* __restrict__ att,
                           const float* __restrict__ aff, const float* __restrict__ g2,
                           const float* __restrict__ b2, float* __restrict__ ao,
                           float* __restrict__ yn) {
    int row = blockIdx.x * 4 + (threadIdx.x >> 6);
    int lane = threadIdx.x & 63;
    float a = aff[row];
    const float* xr = x + (size_t)row * C_;
    const float* atr = att + (size_t)row * C_;
    float o[4];
    float s = 0.f, ss = 0.f;
    #pragma unroll
    for (int j = 0; j < 4; ++j) {
        int c = lane + j * 64;
        float val = (1.f - a) * xr[c] + a * GAIN_ * atr[c];
        o[j] = val;
        s += val;
        ss += val * val;
    }
    s = waveReduceSum(s);
    ss = waveReduceSum(ss);
    float mean = s * (1.f / 256.f);
    float var = ss * (1.f / 256.f) - mean * mean;
    float rstd = rsqrtf(var + LN_EPS_);
    float* aor = ao + (size_t)row * C_;
    float* ynr = yn + (size_t)row * C_;
    #pragma unroll
    for (int j = 0; j < 4; ++j) {
        int c = lane + j * 64;
        aor[c] = o[j];
        ynr[c] = (o[j] - mean) * rstd * g2[c] + b2[c];
    }
}

// MLP layer: out = gelu((xin*mod) @ W + bias); mode 2 additionally applies final gating to d_out
__global__ __launch_bounds__(256) void k_mlp(
    const float* __restrict__ xin, const float* __restrict__ mods, int modIdx,
    const float* __restrict__ W, const float* __restrict__ bias,
    float* __restrict__ out, int mode,
    const float* __restrict__ attn_out, const float* __restrict__ aff) {
    __shared__ __align__(16) float xs[32][65];
    __shared__ __align__(16) float wt[32][64];
    int col0 = blockIdx.x * 64;
    int row0 = blockIdx.y * 64;
    int u = (row0 / V_) % U_;
    const float* msel = mods + (modIdx * U_ + u) * C_;
    int tid = threadIdx.x;
    int a4 = (tid >> 4) * 4;
    int b4 = (tid & 15) * 4;
    float acc[4][4] = {};
    int scl = tid & 31, sr = tid >> 5;
    int wcol = tid & 63, wcc = tid >> 6;
    for (int c0 = 0; c0 < 256; c0 += 32) {
        float mval = msel[c0 + scl];
        #pragma unroll
        for (int it = 0; it < 8; ++it) {
            int r = sr + it * 8;
            xs[scl][r] = xin[(size_t)(row0 + r) * 256 + c0 + scl] * mval;
        }
        #pragma unroll
        for (int it = 0; it < 8; ++it) {
            int c = wcc + it * 4;
            wt[c][wcol] = W[(size_t)(c0 + c) * 256 + col0 + wcol];
        }
        __syncthreads();
        #pragma unroll
        for (int c = 0; c < 32; ++c) {
            const float4 wv = *(const float4*)&wt[c][b4];
            const float x0 = xs[c][a4 + 0];
            const float x1 = xs[c][a4 + 1];
            const float x2 = xs[c][a4 + 2];
            const float x3 = xs[c][a4 + 3];
            acc[0][0] = fmaf(x0, wv.x, acc[0][0]); acc[0][1] = fmaf(x0, wv.y, acc[0][1]);
            acc[0][2] = fmaf(x0, wv.z, acc[0][2]); acc[0][3] = fmaf(x0, wv.w, acc[0][3]);
            acc[1][0] = fmaf(x1, wv.x, acc[1][0]); acc[1][1] = fmaf(x1, wv.y, acc[1][1]);
            acc[1][2] = fmaf(x1, wv.z, acc[1][2]); acc[1][3] = fmaf(x1, wv.w, acc[1][3]);
            acc[2][0] = fmaf(x2, wv.x, acc[2][0]); acc[2][1] = fmaf(x2, wv.y, acc[2][1]);
            acc[2][2] = fmaf(x2, wv.z, acc[2][2]); acc[2][3] = fmaf(x2, wv.w, acc[2][3]);
            acc[3][0] = fmaf(x3, wv.x, acc[3][0]); acc[3][1] = fmaf(x3, wv.y, acc[3][1]);
            acc[3][2] = fmaf(x3, wv.z, acc[3][2]); acc[3][3] = fmaf(x3, wv.w, acc[3][3]);
        }
        __syncthreads();
    }
    #pragma unroll
    for (int i = 0; i < 4; ++i) {
        int row = row0 + a4 + i;
        #pragma unroll
        for (int j = 0; j < 4; ++j) {
            int col = col0 + b4 + j;
            float val = gelu_exact(acc[i][j] + bias[col]);
            if (mode == 1) {
                out[(size_t)row * 256 + col] = val;
            } else {
                float a = aff[row];
                float aov = attn_out[(size_t)row * 256 + col];
                out[(size_t)row * 256 + col] = (1.f - a) * aov + GAIN_ * a * a * val;
            }
        }
    }
}

extern "C" void kernel_launch(void* const* d_in, const int* in_sizes, int n_in,
                              void* d_out, int out_size, void* d_ws, size_t ws_size,
                              hipStream_t stream) {
    const float* variables = (const float*)d_in[0];
    const float* codes     = (const float*)d_in[1];
    const float* affinities= (const float*)d_in[2];
    const float* ln1_g = (const float*)d_in[3];
    const float* ln1_b = (const float*)d_in[4];
    const float* Wq  = (const float*)d_in[5];
    const float* Wcq = (const float*)d_in[6];
    const float* Wk  = (const float*)d_in[7];
    const float* Wck = (const float*)d_in[8];
    const float* Wv  = (const float*)d_in[9];
    const float* Wcv = (const float*)d_in[10];
    const float* bv  = (const float*)d_in[11];
    const float* ln2_g = (const float*)d_in[12];
    const float* ln2_b = (const float*)d_in[13];
    const float* W1  = (const float*)d_in[14];
    const float* Wc1 = (const float*)d_in[15];
    const float* b1m = (const float*)d_in[16];
    const float* W2  = (const float*)d_in[17];
    const float* Wc2 = (const float*)d_in[18];
    const float* b2m = (const float*)d_in[19];

    float* ws   = (float*)d_ws;
    float* mods = ws;                    // 10240
    float* xn   = ws + 10240;            // 2097152 (reused as h1)
    float* qb   = ws + 2107392;          // 4194304 (reused as yn)
    float* kb   = ws + 6301696;          // 4194304
    float* vb   = ws + 10496000;         // 2097152
    float* att  = ws + 12593152;         // 2097152
    float* ao   = ws + 14690304;         // 2097152
    float* h1 = xn;
    float* yn = qb;
    float* outp = (float*)d_out;

    k_mods<<<U_, 256, 0, stream>>>(codes, Wcq, Wck, Wcv, Wc1, Wc2, mods);
    k_ln1<<<(B_ * U_ * V_) / 4, 256, 0, stream>>>(variables, ln1_g, ln1_b, xn);
    k_qkv<<<dim3(20, 128), 256, 0, stream>>>(xn, mods, Wq, Wk, Wv, bv, qb, kb, vb);
    k_attn<<<dim3(8, 128), 256, 0, stream>>>(qb, kb, vb, affinities, att);
    k_gate_ln2<<<(B_ * U_ * V_) / 4, 256, 0, stream>>>(variables, att, affinities,
                                                       ln2_g, ln2_b, ao, yn);
    k_mlp<<<dim3(4, 128), 256, 0, stream>>>(yn, mods, 3, W1, b1m, h1, 1, nullptr, nullptr);
    k_mlp<<<dim3(4, 128), 256, 0, stream>>>(h1, mods, 4, W2, b2m, outp, 2, ao, affinities);
}

// Round 3
// 183.150 us; speedup vs baseline: 2.2072x; 2.2072x over previous
//
#include <hip/hip_runtime.h>
#include <math.h>

#define B_ 2
#define U_ 8
#define V_ 512
#define C_ 256
#define H_ 8
#define R_ 256
#define EPS_ 1e-6f
#define LN_EPS_ 1e-5f
#define GAIN_ 2.5f

typedef __attribute__((ext_vector_type(8))) short bf16x8;
typedef __attribute__((ext_vector_type(4))) float f32x4;
typedef unsigned short ushort_t;

__device__ __forceinline__ ushort_t f2bf(float x) {
    union { float f; unsigned u; } v; v.f = x;
    unsigned r = v.u + 0x7fffu + ((v.u >> 16) & 1u);
    return (ushort_t)(r >> 16);
}

__device__ __forceinline__ float waveReduceSum(float v) {
    #pragma unroll
    for (int m = 1; m < 64; m <<= 1) v += __shfl_xor(v, m);
    return v;
}

__device__ __forceinline__ float gelu_exact(float x) {
    return 0.5f * x * (1.f + erff(x * 0.70710678118654752f));
}

// mods[kind][u][c] = 1 + codes[u] . Wc_kind[:, c]; block 0 also builds biasQKV[1280]
__global__ void k_mods(const float* __restrict__ codes,
                       const float* __restrict__ Wcq, const float* __restrict__ Wck,
                       const float* __restrict__ Wcv, const float* __restrict__ Wc1,
                       const float* __restrict__ Wc2, const float* __restrict__ bv,
                       float* __restrict__ mods, float* __restrict__ biasQ) {
    int u = blockIdx.x, c = threadIdx.x;
    const float* cd = codes + u * 192;
    float aq = 0.f, ak = 0.f, av = 0.f, a1 = 0.f, a2 = 0.f;
    for (int j = 0; j < 192; ++j) {
        float cj = cd[j];
        aq = fmaf(cj, Wcq[j * C_ + c], aq);
        ak = fmaf(cj, Wck[j * C_ + c], ak);
        av = fmaf(cj, Wcv[j * C_ + c], av);
        a1 = fmaf(cj, Wc1[j * R_ + c], a1);
        a2 = fmaf(cj, Wc2[j * R_ + c], a2);
    }
    mods[(0 * U_ + u) * C_ + c] = 1.f + aq;
    mods[(1 * U_ + u) * C_ + c] = 1.f + ak;
    mods[(2 * U_ + u) * C_ + c] = 1.f + av;
    mods[(3 * U_ + u) * C_ + c] = 1.f + a1;
    mods[(4 * U_ + u) * C_ + c] = 1.f + a2;
    if (u == 0) {
        biasQ[c] = 0.f; biasQ[256 + c] = 0.f; biasQ[512 + c] = 0.f;
        biasQ[768 + c] = 0.f; biasQ[1024 + c] = bv[c];
    }
}

// Fold mod into weights, convert to bf16, store TRANSPOSED [u][col][c].
// 896 blocks: [0,256) Wq, [256,512) Wk, [512,640) Wv, [640,768) W1, [768,896) W2.
__global__ __launch_bounds__(256) void k_fold(
    const float* __restrict__ Wq, const float* __restrict__ Wk,
    const float* __restrict__ Wv, const float* __restrict__ W1,
    const float* __restrict__ W2, const float* __restrict__ mods,
    ushort_t* __restrict__ wqkvT, ushort_t* __restrict__ w1T,
    ushort_t* __restrict__ w2T) {
    __shared__ ushort_t T[64][65];
    int id = blockIdx.x;
    const float* W; int ldw, modIdx, colAdd, tilesPerU, base;
    ushort_t* dst; int dstCols;
    if (id < 256)      { base = 0;   W = Wq; ldw = 512; modIdx = 0; colAdd = 0;    dst = wqkvT; dstCols = 1280; tilesPerU = 32; }
    else if (id < 512) { base = 256; W = Wk; ldw = 512; modIdx = 1; colAdd = 512;  dst = wqkvT; dstCols = 1280; tilesPerU = 32; }
    else if (id < 640) { base = 512; W = Wv; ldw = 256; modIdx = 2; colAdd = 1024; dst = wqkvT; dstCols = 1280; tilesPerU = 16; }
    else if (id < 768) { base = 640; W = W1; ldw = 256; modIdx = 3; colAdd = 0;    dst = w1T;  dstCols = 256;  tilesPerU = 16; }
    else               { base = 768; W = W2; ldw = 256; modIdx = 4; colAdd = 0;    dst = w2T;  dstCols = 256;  tilesPerU = 16; }
    int local = id - base;
    int u = local / tilesPerU;
    int t = local % tilesPerU;
    int nColTiles = ldw / 64;
    int c0 = (t / nColTiles) * 64;
    int col0 = (t % nColTiles) * 64;
    const float* modRow = mods + (modIdx * U_ + u) * C_;
    int tid = threadIdx.x;
    int cl = tid >> 4;            // c-row within pass
    int cg = (tid & 15) * 4;      // 4 cols
    #pragma unroll
    for (int it = 0; it < 4; ++it) {
        int c = cl + it * 16;
        float m = modRow[c0 + c];
        float4 wv = *(const float4*)&W[(size_t)(c0 + c) * ldw + col0 + cg];
        T[c][cg + 0] = f2bf(wv.x * m);
        T[c][cg + 1] = f2bf(wv.y * m);
        T[c][cg + 2] = f2bf(wv.z * m);
        T[c][cg + 3] = f2bf(wv.w * m);
    }
    __syncthreads();
    int j = tid >> 2;             // col within tile
    int ch = (tid & 3) * 16;      // c chunk
    ushort_t tmp[16];
    #pragma unroll
    for (int i = 0; i < 16; ++i) tmp[i] = T[ch + i][j];
    ushort_t* o = dst + ((size_t)u * dstCols + colAdd + col0 + j) * 256 + c0 + ch;
    *(bf16x8*)&o[0] = *(const bf16x8*)&tmp[0];
    *(bf16x8*)&o[8] = *(const bf16x8*)&tmp[8];
}

// LayerNorm over C=256 -> bf16; one row per wave, lane handles 4 contiguous cols.
__global__ void k_ln1(const float* __restrict__ x, const float* __restrict__ g,
                      const float* __restrict__ b, ushort_t* __restrict__ xnb) {
    int row = blockIdx.x * 4 + (threadIdx.x >> 6);
    int lane = threadIdx.x & 63;
    const float* xr = x + (size_t)row * C_;
    float4 v = *(const float4*)&xr[lane * 4];
    float s = v.x + v.y + v.z + v.w;
    float ss = v.x * v.x + v.y * v.y + v.z * v.z + v.w * v.w;
    s = waveReduceSum(s); ss = waveReduceSum(ss);
    float mean = s * (1.f / 256.f);
    float var = ss * (1.f / 256.f) - mean * mean;
    float rstd = rsqrtf(var + LN_EPS_);
    float4 gg = *(const float4*)&g[lane * 4];
    float4 bb = *(const float4*)&b[lane * 4];
    unsigned lo = (unsigned)f2bf((v.x - mean) * rstd * gg.x + bb.x)
                | ((unsigned)f2bf((v.y - mean) * rstd * gg.y + bb.y) << 16);
    unsigned hi = (unsigned)f2bf((v.z - mean) * rstd * gg.z + bb.z)
                | ((unsigned)f2bf((v.w - mean) * rstd * gg.w + bb.w) << 16);
    uint2 pk; pk.x = lo; pk.y = hi;
    *(uint2*)&xnb[(size_t)row * C_ + lane * 4] = pk;
}

// Generic MFMA GEMM: out[row, col] = act(X[row,:] @ W_u[:, col] + bias[col])
// MODE 0: bf16 out (QKV). MODE 1: gelu, bf16 out. MODE 2: gelu + gating, f32 out.
template<int MODE>
__global__ __launch_bounds__(256) void k_gemm(
    const ushort_t* __restrict__ X, const ushort_t* __restrict__ WT, int wPerU,
    const float* __restrict__ bias, ushort_t* __restrict__ outB, int ldo,
    float* __restrict__ outF, const float* __restrict__ ao,
    const float* __restrict__ aff) {
    __shared__ __align__(16) ushort_t xs[64][72];
    __shared__ __align__(16) ushort_t wt[64][72];
    int col0 = blockIdx.x * 64;
    int row0 = blockIdx.y * 64;
    int u = (row0 >> 9) & 7;
    const ushort_t* Wu = WT + ((size_t)u * wPerU + col0) * 256;
    int tid = threadIdx.x;
    int w = tid >> 6, l = tid & 63;
    int lr = l & 15, lg = l >> 4;
    f32x4 acc[4] = {};
    for (int k0 = 0; k0 < 256; k0 += 64) {
        int r1 = tid >> 3, ko1 = (tid & 7) * 8;
        int r2 = (tid + 256) >> 3, ko2 = ((tid + 256) & 7) * 8;
        *(bf16x8*)&xs[r1][ko1] = *(const bf16x8*)&X[(size_t)(row0 + r1) * 256 + k0 + ko1];
        *(bf16x8*)&xs[r2][ko2] = *(const bf16x8*)&X[(size_t)(row0 + r2) * 256 + k0 + ko2];
        *(bf16x8*)&wt[r1][ko1] = *(const bf16x8*)&Wu[(size_t)r1 * 256 + k0 + ko1];
        *(bf16x8*)&wt[r2][ko2] = *(const bf16x8*)&Wu[(size_t)r2 * 256 + k0 + ko2];
        __syncthreads();
        #pragma unroll
        for (int n = 0; n < 4; ++n) {
            #pragma unroll
            for (int kk = 0; kk < 2; ++kk) {
                bf16x8 a = *(const bf16x8*)&xs[w * 16 + lr][kk * 32 + lg * 8];
                bf16x8 bb = *(const bf16x8*)&wt[n * 16 + lr][kk * 32 + lg * 8];
                acc[n] = __builtin_amdgcn_mfma_f32_16x16x32_bf16(a, bb, acc[n], 0, 0, 0);
            }
        }
        __syncthreads();
    }
    #pragma unroll
    for (int n = 0; n < 4; ++n) {
        int col = col0 + n * 16 + lr;
        float bval = bias[col];
        #pragma unroll
        for (int i = 0; i < 4; ++i) {
            int row = row0 + w * 16 + lg * 4 + i;
            float v = acc[n][i] + bval;
            if (MODE >= 1) v = gelu_exact(v);
            if (MODE == 2) {
                float a = aff[row];
                float aov = ao[(size_t)row * 256 + col];
                outF[(size_t)row * 256 + col] = (1.f - a) * aov + GAIN_ * a * a * v;
            } else {
                outB[(size_t)row * ldo + col] = f2bf(v);
            }
        }
    }
}

// Attention per (bu,h,64-row tile) with MFMA. qkv: [8192][1280] bf16 (Q|K|V).
// att[r] = a_r * sum_s(a_s e v) / (a_r * sum_s(a_s e) + EPS * sum_s(e))
__global__ __launch_bounds__(256) void k_attn(
    const ushort_t* __restrict__ qkv, const float* __restrict__ aff,
    float* __restrict__ att) {
    __shared__ __align__(16) ushort_t Qs[64][72];
    __shared__ __align__(16) ushort_t Ks[64][72];
    __shared__ __align__(16) ushort_t Ps[64][72];
    __shared__ __align__(16) ushort_t Vt[32][72];
    __shared__ float As[64];
    int r0 = blockIdx.x * 64;
    int buh = blockIdx.y;
    int h = buh & 7, bu = buh >> 3;
    const ushort_t* base = qkv + (size_t)bu * 512 * 1280;
    int tid = threadIdx.x;
    int w = tid >> 6, l = tid & 63;
    int lr = l & 15, lg = l >> 4;
    {   // stage Q tile [64 rows][64 d]
        int rA = tid >> 3, koA = (tid & 7) * 8;
        int rB = (tid + 256) >> 3, koB = ((tid + 256) & 7) * 8;
        *(bf16x8*)&Qs[rA][koA] = *(const bf16x8*)&base[(size_t)(r0 + rA) * 1280 + h * 64 + koA];
        *(bf16x8*)&Qs[rB][koB] = *(const bf16x8*)&base[(size_t)(r0 + rB) * 1280 + h * 64 + koB];
    }
    f32x4 pacc[2] = {};
    float wsum[4] = {}, asum[4] = {};
    for (int s0 = 0; s0 < 512; s0 += 64) {
        {   // stage K tile
            int rA = tid >> 3, koA = (tid & 7) * 8;
            int rB = (tid + 256) >> 3, koB = ((tid + 256) & 7) * 8;
            *(bf16x8*)&Ks[rA][koA] = *(const bf16x8*)&base[(size_t)(s0 + rA) * 1280 + 512 + h * 64 + koA];
            *(bf16x8*)&Ks[rB][koB] = *(const bf16x8*)&base[(size_t)(s0 + rB) * 1280 + 512 + h * 64 + koB];
        }
        {   // stage V transposed: Vt[c][s]
            int c = tid & 31, sblk = (tid >> 5) * 8;
            ushort_t tmp[8];
            #pragma unroll
            for (int jj = 0; jj < 8; ++jj)
                tmp[jj] = base[(size_t)(s0 + sblk + jj) * 1280 + 1024 + h * 32 + c];
            *(bf16x8*)&Vt[c][sblk] = *(const bf16x8*)&tmp[0];
        }
        if (tid < 64) As[tid] = aff[bu * 512 + s0 + tid];
        __syncthreads();
        // QK^T + exp + P write (wave-local rows)
        #pragma unroll
        for (int n = 0; n < 4; ++n) {
            f32x4 sc = {};
            #pragma unroll
            for (int kk = 0; kk < 2; ++kk) {
                bf16x8 a = *(const bf16x8*)&Qs[w * 16 + lr][kk * 32 + lg * 8];
                bf16x8 bb = *(const bf16x8*)&Ks[n * 16 + lr][kk * 32 + lg * 8];
                sc = __builtin_amdgcn_mfma_f32_16x16x32_bf16(a, bb, sc, 0, 0, 0);
            }
            int scol = n * 16 + lr;
            float av = As[scol];
            #pragma unroll
            for (int i = 0; i < 4; ++i) {
                float e = __expf(sc[i]);
                float ae = e * av;
                wsum[i] += e; asum[i] += ae;
                Ps[w * 16 + lg * 4 + i][scol] = f2bf(ae);
            }
        }
        // PV (P rows are wave-local; Vt guarded by the staging barrier)
        #pragma unroll
        for (int n = 0; n < 2; ++n) {
            #pragma unroll
            for (int kk = 0; kk < 2; ++kk) {
                bf16x8 a = *(const bf16x8*)&Ps[w * 16 + lr][kk * 32 + lg * 8];
                bf16x8 bb = *(const bf16x8*)&Vt[n * 16 + lr][kk * 32 + lg * 8];
                pacc[n] = __builtin_amdgcn_mfma_f32_16x16x32_bf16(a, bb, pacc[n], 0, 0, 0);
            }
        }
        __syncthreads();
    }
    #pragma unroll
    for (int m = 1; m < 16; m <<= 1) {
        #pragma unroll
        for (int i = 0; i < 4; ++i) {
            wsum[i] += __shfl_xor(wsum[i], m);
            asum[i] += __shfl_xor(asum[i], m);
        }
    }
    #pragma unroll
    for (int i = 0; i < 4; ++i) {
        int r = r0 + w * 16 + lg * 4 + i;
        float ar = aff[bu * 512 + r];
        float scale = ar / (ar * asum[i] + EPS_ * wsum[i]);
        float* ob = att + ((size_t)bu * 512 + r) * 256 + h * 32;
        ob[lr]      = pacc[0][i] * scale;
        ob[16 + lr] = pacc[1][i] * scale;
    }
}

// gated residual + LN2: ao = (1-a)x + a*GAIN*att (f32); ynb = bf16(LN(ao)*g2+b2)
__global__ void k_gate_ln2(const float* __restrict__ x, const float* __restrict__ att,
                           const float* __restrict__ aff, const float* __restrict__ g2,
                           const float* __restrict__ b2, float* __restrict__ ao,
                           ushort_t* __restrict__ ynb) {
    int row = blockIdx.x * 4 + (threadIdx.x >> 6);
    int lane = threadIdx.x & 63;
    float a = aff[row];
    const float* xr = x + (size_t)row * C_;
    const float* atr = att + (size_t)row * C_;
    float4 xv = *(const float4*)&xr[lane * 4];
    float4 av = *(const float4*)&atr[lane * 4];
    float4 o;
    o.x = (1.f - a) * xv.x + a * GAIN_ * av.x;
    o.y = (1.f - a) * xv.y + a * GAIN_ * av.y;
    o.z = (1.f - a) * xv.z + a * GAIN_ * av.z;
    o.w = (1.f - a) * xv.w + a * GAIN_ * av.w;
    float s = o.x + o.y + o.z + o.w;
    float ss = o.x * o.x + o.y * o.y + o.z * o.z + o.w * o.w;
    s = waveReduceSum(s); ss = waveReduceSum(ss);
    float mean = s * (1.f / 256.f);
    float var = ss * (1.f / 256.f) - mean * mean;
    float rstd = rsqrtf(var + LN_EPS_);
    *(float4*)&ao[(size_t)row * C_ + lane * 4] = o;
    float4 gg = *(const float4*)&g2[lane * 4];
    float4 bb = *(const float4*)&b2[lane * 4];
    unsigned lo = (unsigned)f2bf((o.x - mean) * rstd * gg.x + bb.x)
                | ((unsigned)f2bf((o.y - mean) * rstd * gg.y + bb.y) << 16);
    unsigned hi = (unsigned)f2bf((o.z - mean) * rstd * gg.z + bb.z)
                | ((unsigned)f2bf((o.w - mean) * rstd * gg.w + bb.w) << 16);
    uint2 pk; pk.x = lo; pk.y = hi;
    *(uint2*)&ynb[(size_t)row * C_ + lane * 4] = pk;
}

extern "C" void kernel_launch(void* const* d_in, const int* in_sizes, int n_in,
                              void* d_out, int out_size, void* d_ws, size_t ws_size,
                              hipStream_t stream) {
    const float* variables  = (const float*)d_in[0];
    const float* codes      = (const float*)d_in[1];
    const float* affinities = (const float*)d_in[2];
    const float* ln1_g = (const float*)d_in[3];
    const float* ln1_b = (const float*)d_in[4];
    const float* Wq  = (const float*)d_in[5];
    const float* Wcq = (const float*)d_in[6];
    const float* Wk  = (const float*)d_in[7];
    const float* Wck = (const float*)d_in[8];
    const float* Wv  = (const float*)d_in[9];
    const float* Wcv = (const float*)d_in[10];
    const float* bv  = (const float*)d_in[11];
    const float* ln2_g = (const float*)d_in[12];
    const float* ln2_b = (const float*)d_in[13];
    const float* W1  = (const float*)d_in[14];
    const float* Wc1 = (const float*)d_in[15];
    const float* b1m = (const float*)d_in[16];
    const float* W2  = (const float*)d_in[17];
    const float* Wc2 = (const float*)d_in[18];
    const float* b2m = (const float*)d_in[19];

    char* p = (char*)d_ws;
    float* modsF = (float*)p;   p += 40960;        // [5][8][256] f32
    float* biasQ = (float*)p;   p += 5120;         // [1280] f32
    float* attF  = (float*)p;   p += 8388608;      // [8192][256] f32
    float* aoF   = (float*)p;   p += 8388608;      // [8192][256] f32
    ushort_t* xnb   = (ushort_t*)p; p += 4194304;  // [8192][256] bf16
    ushort_t* wqkvT = (ushort_t*)p; p += 5242880;  // [8][1280][256] bf16
    ushort_t* w1T   = (ushort_t*)p; p += 1048576;  // [8][256][256] bf16
    ushort_t* w2T   = (ushort_t*)p; p += 1048576;  // [8][256][256] bf16
    ushort_t* qkvb  = (ushort_t*)p; p += 20971520; // [8192][1280] bf16
    ushort_t* ynb   = (ushort_t*)p; p += 4194304;  // [8192][256] bf16
    ushort_t* h1b   = (ushort_t*)p; p += 4194304;  // [8192][256] bf16
    float* outp = (float*)d_out;

    k_mods<<<U_, 256, 0, stream>>>(codes, Wcq, Wck, Wcv, Wc1, Wc2, bv, modsF, biasQ);
    k_fold<<<896, 256, 0, stream>>>(Wq, Wk, Wv, W1, W2, modsF, wqkvT, w1T, w2T);
    k_ln1<<<2048, 256, 0, stream>>>(variables, ln1_g, ln1_b, xnb);
    k_gemm<0><<<dim3(20, 128), 256, 0, stream>>>(xnb, wqkvT, 1280, biasQ, qkvb, 1280,
                                                 nullptr, nullptr, nullptr);
    k_attn<<<dim3(8, 128), 256, 0, stream>>>(qkvb, affinities, attF);
    k_gate_ln2<<<2048, 256, 0, stream>>>(variables, attF, affinities, ln2_g, ln2_b, aoF, ynb);
    k_gemm<1><<<dim3(4, 128), 256, 0, stream>>>(ynb, w1T, 256, b1m, h1b, 256,
                                                nullptr, nullptr, nullptr);
    k_gemm<2><<<dim3(4, 128), 256, 0, stream>>>(h1b, w2T, 256, b2m, nullptr, 256,
                                                outp, aoF, affinities);
}

// Round 4
// 175.596 us; speedup vs baseline: 2.3022x; 1.0430x over previous
//
#include <hip/hip_runtime.h>
#include <math.h>

#define B_ 2
#define U_ 8
#define V_ 512
#define C_ 256
#define H_ 8
#define R_ 256
#define EPS_ 1e-6f
#define LN_EPS_ 1e-5f
#define GAIN_ 2.5f

typedef __attribute__((ext_vector_type(8))) short bf16x8;
typedef __attribute__((ext_vector_type(4))) float f32x4;
typedef unsigned short ushort_t;

__device__ __forceinline__ ushort_t f2bf(float x) {
    union { float f; unsigned u; } v; v.f = x;
    unsigned r = v.u + 0x7fffu + ((v.u >> 16) & 1u);
    return (ushort_t)(r >> 16);
}

__device__ __forceinline__ float waveReduceSum(float v) {
    #pragma unroll
    for (int m = 1; m < 64; m <<= 1) v += __shfl_xor(v, m);
    return v;
}

__device__ __forceinline__ float gelu_exact(float x) {
    return 0.5f * x * (1.f + erff(x * 0.70710678118654752f));
}

// mods[kind][u][c] = 1 + codes[u] . Wc_kind[:, c]. Grid 40 = (kind*8+u).
// Block 0 also builds biasQ[1280].
__global__ void k_mods(const float* __restrict__ codes,
                       const float* __restrict__ Wcq, const float* __restrict__ Wck,
                       const float* __restrict__ Wcv, const float* __restrict__ Wc1,
                       const float* __restrict__ Wc2, const float* __restrict__ bv,
                       float* __restrict__ mods, float* __restrict__ biasQ) {
    int id = blockIdx.x;           // 0..39
    int kind = id >> 3, u = id & 7;
    const float* Wc = (kind == 0) ? Wcq : (kind == 1) ? Wck :
                      (kind == 2) ? Wcv : (kind == 3) ? Wc1 : Wc2;
    int c = threadIdx.x;
    const float* cd = codes + u * 192;
    float a = 0.f;
    for (int j = 0; j < 192; ++j) a = fmaf(cd[j], Wc[j * 256 + c], a);
    mods[id * 256 + c] = 1.f + a;
    if (id == 0) {
        biasQ[c] = 0.f; biasQ[256 + c] = 0.f; biasQ[512 + c] = 0.f;
        biasQ[768 + c] = 0.f; biasQ[1024 + c] = bv[c];
    }
}

// Fold mod into weights, convert to bf16, store TRANSPOSED [u][col][c].
// 896 blocks: [0,256) Wq, [256,512) Wk, [512,640) Wv, [640,768) W1, [768,896) W2.
__global__ __launch_bounds__(256) void k_fold(
    const float* __restrict__ Wq, const float* __restrict__ Wk,
    const float* __restrict__ Wv, const float* __restrict__ W1,
    const float* __restrict__ W2, const float* __restrict__ mods,
    ushort_t* __restrict__ wqkvT, ushort_t* __restrict__ w1T,
    ushort_t* __restrict__ w2T) {
    __shared__ ushort_t T[64][65];
    int id = blockIdx.x;
    const float* W; int ldw, modIdx, colAdd, tilesPerU, base;
    ushort_t* dst; int dstCols;
    if (id < 256)      { base = 0;   W = Wq; ldw = 512; modIdx = 0; colAdd = 0;    dst = wqkvT; dstCols = 1280; tilesPerU = 32; }
    else if (id < 512) { base = 256; W = Wk; ldw = 512; modIdx = 1; colAdd = 512;  dst = wqkvT; dstCols = 1280; tilesPerU = 32; }
    else if (id < 640) { base = 512; W = Wv; ldw = 256; modIdx = 2; colAdd = 1024; dst = wqkvT; dstCols = 1280; tilesPerU = 16; }
    else if (id < 768) { base = 640; W = W1; ldw = 256; modIdx = 3; colAdd = 0;    dst = w1T;  dstCols = 256;  tilesPerU = 16; }
    else               { base = 768; W = W2; ldw = 256; modIdx = 4; colAdd = 0;    dst = w2T;  dstCols = 256;  tilesPerU = 16; }
    int local = id - base;
    int u = local / tilesPerU;
    int t = local % tilesPerU;
    int nColTiles = ldw / 64;
    int c0 = (t / nColTiles) * 64;
    int col0 = (t % nColTiles) * 64;
    const float* modRow = mods + (modIdx * U_ + u) * C_;
    int tid = threadIdx.x;
    int cl = tid >> 4;
    int cg = (tid & 15) * 4;
    #pragma unroll
    for (int it = 0; it < 4; ++it) {
        int c = cl + it * 16;
        float m = modRow[c0 + c];
        float4 wv = *(const float4*)&W[(size_t)(c0 + c) * ldw + col0 + cg];
        T[c][cg + 0] = f2bf(wv.x * m);
        T[c][cg + 1] = f2bf(wv.y * m);
        T[c][cg + 2] = f2bf(wv.z * m);
        T[c][cg + 3] = f2bf(wv.w * m);
    }
    __syncthreads();
    int j = tid >> 2;
    int ch = (tid & 3) * 16;
    ushort_t tmp[16];
    #pragma unroll
    for (int i = 0; i < 16; ++i) tmp[i] = T[ch + i][j];
    ushort_t* o = dst + ((size_t)u * dstCols + colAdd + col0 + j) * 256 + c0 + ch;
    *(bf16x8*)&o[0] = *(const bf16x8*)&tmp[0];
    *(bf16x8*)&o[8] = *(const bf16x8*)&tmp[8];
}

// LayerNorm over C=256 -> bf16; one row per wave.
__global__ void k_ln1(const float* __restrict__ x, const float* __restrict__ g,
                      const float* __restrict__ b, ushort_t* __restrict__ xnb) {
    int row = blockIdx.x * 4 + (threadIdx.x >> 6);
    int lane = threadIdx.x & 63;
    const float* xr = x + (size_t)row * C_;
    float4 v = *(const float4*)&xr[lane * 4];
    float s = v.x + v.y + v.z + v.w;
    float ss = v.x * v.x + v.y * v.y + v.z * v.z + v.w * v.w;
    s = waveReduceSum(s); ss = waveReduceSum(ss);
    float mean = s * (1.f / 256.f);
    float var = ss * (1.f / 256.f) - mean * mean;
    float rstd = rsqrtf(var + LN_EPS_);
    float4 gg = *(const float4*)&g[lane * 4];
    float4 bb = *(const float4*)&b[lane * 4];
    unsigned lo = (unsigned)f2bf((v.x - mean) * rstd * gg.x + bb.x)
                | ((unsigned)f2bf((v.y - mean) * rstd * gg.y + bb.y) << 16);
    unsigned hi = (unsigned)f2bf((v.z - mean) * rstd * gg.z + bb.z)
                | ((unsigned)f2bf((v.w - mean) * rstd * gg.w + bb.w) << 16);
    uint2 pk; pk.x = lo; pk.y = hi;
    *(uint2*)&xnb[(size_t)row * C_ + lane * 4] = pk;
}

// QKV GEMM, 128x128 tiles, 4 waves in 2x2 quadrants, K-step 64.
// out = qkv [8192][1280] bf16; V region also written transposed to vT[bu*8+h][c][s].
__global__ __launch_bounds__(256) void k_qkv(
    const ushort_t* __restrict__ X, const ushort_t* __restrict__ WT,
    const float* __restrict__ biasQ, ushort_t* __restrict__ out,
    ushort_t* __restrict__ vT) {
    __shared__ __align__(16) ushort_t xs[128][72];
    __shared__ __align__(16) ushort_t wt[128][72];
    int col0 = blockIdx.x * 128;
    int row0 = blockIdx.y * 128;
    int u = (row0 >> 9) & 7;
    const ushort_t* Wu = WT + (size_t)(u * 1280 + col0) * 256;
    int tid = threadIdx.x;
    int w = tid >> 6, l = tid & 63;
    int lr = l & 15, lg = l >> 4;
    int wm = w >> 1, wn = w & 1;
    f32x4 acc[4][4] = {};
    int sr = tid >> 3, sko = (tid & 7) * 8;
    for (int k0 = 0; k0 < 256; k0 += 64) {
        #pragma unroll
        for (int it = 0; it < 4; ++it) {
            int r = sr + it * 32;
            *(bf16x8*)&xs[r][sko] = *(const bf16x8*)&X[(size_t)(row0 + r) * 256 + k0 + sko];
            *(bf16x8*)&wt[r][sko] = *(const bf16x8*)&Wu[(size_t)r * 256 + k0 + sko];
        }
        __syncthreads();
        #pragma unroll
        for (int m = 0; m < 4; ++m) {
            #pragma unroll
            for (int kk = 0; kk < 2; ++kk) {
                bf16x8 a = *(const bf16x8*)&xs[wm * 64 + m * 16 + lr][kk * 32 + lg * 8];
                #pragma unroll
                for (int n = 0; n < 4; ++n) {
                    bf16x8 bb = *(const bf16x8*)&wt[wn * 64 + n * 16 + lr][kk * 32 + lg * 8];
                    acc[m][n] = __builtin_amdgcn_mfma_f32_16x16x32_bf16(a, bb, acc[m][n], 0, 0, 0);
                }
            }
        }
        __syncthreads();
    }
    #pragma unroll
    for (int m = 0; m < 4; ++m) {
        int rowb = row0 + wm * 64 + m * 16 + lg * 4;
        #pragma unroll
        for (int n = 0; n < 4; ++n) {
            int col = col0 + wn * 64 + n * 16 + lr;
            float bval = biasQ[col];
            ushort_t pk4[4];
            #pragma unroll
            for (int i = 0; i < 4; ++i) {
                float v = acc[m][n][i] + bval;
                pk4[i] = f2bf(v);
                out[(size_t)(rowb + i) * 1280 + col] = pk4[i];
            }
            if (col >= 1024) {   // V: also store transposed [bu*8+h][c][s]
                int hh = (col - 1024) >> 5, cc = (col - 1024) & 31;
                int bu = rowb >> 9;
                uint2 pw;
                pw.x = (unsigned)pk4[0] | ((unsigned)pk4[1] << 16);
                pw.y = (unsigned)pk4[2] | ((unsigned)pk4[3] << 16);
                *(uint2*)&vT[(size_t)((bu * 8 + hh) * 32 + cc) * 512 + (rowb & 511)] = pw;
            }
        }
    }
}

// Attention per (bu,h,64-row tile). Swapped QK^T (mfma(K,Q)) so each lane owns
// consecutive-s scores at fixed q-row: P written as b64, sums lane-local.
// T14 async-stage: next K/V global loads issued before compute, LDS-write after barrier.
// Grid 1024 linear with XCD swizzle: blocks sharing (bu) K/V land on one XCD.
__global__ __launch_bounds__(256) void k_attn(
    const ushort_t* __restrict__ qkv, const ushort_t* __restrict__ vT,
    const float* __restrict__ aff, float* __restrict__ att) {
    __shared__ __align__(16) ushort_t Qs[64][72];
    __shared__ __align__(16) ushort_t Ks[64][72];
    __shared__ __align__(16) ushort_t Pt[64][72];
    __shared__ __align__(16) ushort_t Vt[32][72];
    __shared__ float As[64];
    int id = blockIdx.x;
    int xcd = id & 7, sl = id >> 3;        // 8 XCDs x 128 slots
    int bu = xcd + 8 * (sl >> 6);          // 2 bu per XCD -> K/V slice L2-resident
    int inr = sl & 63;
    int h = inr & 7;
    int r0 = (inr >> 3) * 64;
    const ushort_t* base = qkv + (size_t)bu * 512 * 1280;
    const ushort_t* vbase = vT + (size_t)((bu * 8 + h) * 32) * 512;
    int tid = threadIdx.x;
    int w = tid >> 6, l = tid & 63;
    int lr = l & 15, lg = l >> 4;
    int sr = tid >> 3, sko = (tid & 7) * 8;
    // stage Q once
    *(bf16x8*)&Qs[sr][sko]      = *(const bf16x8*)&base[(size_t)(r0 + sr) * 1280 + h * 64 + sko];
    *(bf16x8*)&Qs[sr + 32][sko] = *(const bf16x8*)&base[(size_t)(r0 + sr + 32) * 1280 + h * 64 + sko];
    // prologue: tile 0 K/V/aff
    bf16x8 kr0 = *(const bf16x8*)&base[(size_t)sr * 1280 + 512 + h * 64 + sko];
    bf16x8 kr1 = *(const bf16x8*)&base[(size_t)(sr + 32) * 1280 + 512 + h * 64 + sko];
    bf16x8 vr  = *(const bf16x8*)&vbase[(size_t)sr * 512 + sko];   // sr<32 rows c, else dup-safe? no:
    // V staging uses c=tid>>3 in 0..31 only for tid<256: c = tid>>3 covers 0..31; rows 32.. handled below
    float afv = (tid < 64) ? aff[bu * 512 + tid] : 0.f;
    *(bf16x8*)&Ks[sr][sko] = kr0;
    *(bf16x8*)&Ks[sr + 32][sko] = kr1;
    if (sr < 32) *(bf16x8*)&Vt[sr][sko] = vr;
    if (tid < 64) As[tid] = afv;
    __syncthreads();
    float wsum = 0.f, asum = 0.f;
    f32x4 pacc[2] = {};
    for (int t = 0; t < 8; ++t) {
        int s0n = (t + 1) * 64;
        if (t < 7) {
            kr0 = *(const bf16x8*)&base[(size_t)(s0n + sr) * 1280 + 512 + h * 64 + sko];
            kr1 = *(const bf16x8*)&base[(size_t)(s0n + sr + 32) * 1280 + 512 + h * 64 + sko];
            if (sr < 32) vr = *(const bf16x8*)&vbase[(size_t)sr * 512 + s0n + sko];
            if (tid < 64) afv = aff[bu * 512 + s0n + tid];
        }
        // swapped QK^T: sc[i] = score[s = n*16+lg*4+i][q = w*16+lr]
        #pragma unroll
        for (int n = 0; n < 4; ++n) {
            f32x4 sc = {};
            #pragma unroll
            for (int kk = 0; kk < 2; ++kk) {
                bf16x8 ka = *(const bf16x8*)&Ks[n * 16 + lr][kk * 32 + lg * 8];
                bf16x8 qb = *(const bf16x8*)&Qs[w * 16 + lr][kk * 32 + lg * 8];
                sc = __builtin_amdgcn_mfma_f32_16x16x32_bf16(ka, qb, sc, 0, 0, 0);
            }
            float4 a4 = *(const float4*)&As[n * 16 + lg * 4];
            float e0 = __expf(sc[0]), e1 = __expf(sc[1]);
            float e2 = __expf(sc[2]), e3 = __expf(sc[3]);
            wsum += (e0 + e1) + (e2 + e3);
            float ae0 = e0 * a4.x, ae1 = e1 * a4.y, ae2 = e2 * a4.z, ae3 = e3 * a4.w;
            asum += (ae0 + ae1) + (ae2 + ae3);
            uint2 pw;
            pw.x = (unsigned)f2bf(ae0) | ((unsigned)f2bf(ae1) << 16);
            pw.y = (unsigned)f2bf(ae2) | ((unsigned)f2bf(ae3) << 16);
            *(uint2*)&Pt[w * 16 + lr][n * 16 + lg * 4] = pw;
        }
        // PV: pacc[n2] += Pt(q rows) x Vt(c cols); Pt wave-local, no barrier needed
        #pragma unroll
        for (int n = 0; n < 2; ++n) {
            #pragma unroll
            for (int kk = 0; kk < 2; ++kk) {
                bf16x8 pa = *(const bf16x8*)&Pt[w * 16 + lr][kk * 32 + lg * 8];
                bf16x8 vb = *(const bf16x8*)&Vt[n * 16 + lr][kk * 32 + lg * 8];
                pacc[n] = __builtin_amdgcn_mfma_f32_16x16x32_bf16(pa, vb, pacc[n], 0, 0, 0);
            }
        }
        __syncthreads();
        if (t < 7) {
            *(bf16x8*)&Ks[sr][sko] = kr0;
            *(bf16x8*)&Ks[sr + 32][sko] = kr1;
            if (sr < 32) *(bf16x8*)&Vt[sr][sko] = vr;
            if (tid < 64) As[tid] = afv;
            __syncthreads();
        }
    }
    // per-q sums live at lane lr=q; reduce over lg groups
    asum += __shfl_xor(asum, 16); asum += __shfl_xor(asum, 32);
    wsum += __shfl_xor(wsum, 16); wsum += __shfl_xor(wsum, 32);
    float ar = aff[bu * 512 + r0 + w * 16 + lr];
    float scale = ar / (ar * asum + EPS_ * wsum);
    #pragma unroll
    for (int i = 0; i < 4; ++i) {
        float sc_i = __shfl(scale, lg * 4 + i);
        int q = r0 + w * 16 + lg * 4 + i;
        float* ob = att + ((size_t)bu * 512 + q) * 256 + h * 32;
        ob[lr]      = pacc[0][i] * sc_i;
        ob[16 + lr] = pacc[1][i] * sc_i;
    }
}

// gated residual + LN2: ao = (1-a)x + a*GAIN*att (f32); ynb = bf16(LN(ao)*g2+b2)
__global__ void k_gate_ln2(const float* __restrict__ x, const float* __restrict__ att,
                           const float* __restrict__ aff, const float* __restrict__ g2,
                           const float* __restrict__ b2, float* __restrict__ ao,
                           ushort_t* __restrict__ ynb) {
    int row = blockIdx.x * 4 + (threadIdx.x >> 6);
    int lane = threadIdx.x & 63;
    float a = aff[row];
    const float* xr = x + (size_t)row * C_;
    const float* atr = att + (size_t)row * C_;
    float4 xv = *(const float4*)&xr[lane * 4];
    float4 av = *(const float4*)&atr[lane * 4];
    float4 o;
    o.x = (1.f - a) * xv.x + a * GAIN_ * av.x;
    o.y = (1.f - a) * xv.y + a * GAIN_ * av.y;
    o.z = (1.f - a) * xv.z + a * GAIN_ * av.z;
    o.w = (1.f - a) * xv.w + a * GAIN_ * av.w;
    float s = o.x + o.y + o.z + o.w;
    float ss = o.x * o.x + o.y * o.y + o.z * o.z + o.w * o.w;
    s = waveReduceSum(s); ss = waveReduceSum(ss);
    float mean = s * (1.f / 256.f);
    float var = ss * (1.f / 256.f) - mean * mean;
    float rstd = rsqrtf(var + LN_EPS_);
    *(float4*)&ao[(size_t)row * C_ + lane * 4] = o;
    float4 gg = *(const float4*)&g2[lane * 4];
    float4 bb = *(const float4*)&b2[lane * 4];
    unsigned lo = (unsigned)f2bf((o.x - mean) * rstd * gg.x + bb.x)
                | ((unsigned)f2bf((o.y - mean) * rstd * gg.y + bb.y) << 16);
    unsigned hi = (unsigned)f2bf((o.z - mean) * rstd * gg.z + bb.z)
                | ((unsigned)f2bf((o.w - mean) * rstd * gg.w + bb.w) << 16);
    uint2 pk; pk.x = lo; pk.y = hi;
    *(uint2*)&ynb[(size_t)row * C_ + lane * 4] = pk;
}

// MLP GEMM 64x64 tiles: MODE 1: gelu, bf16 out. MODE 2: gelu + gating, f32 out.
template<int MODE>
__global__ __launch_bounds__(256) void k_gemm(
    const ushort_t* __restrict__ X, const ushort_t* __restrict__ WT, int wPerU,
    const float* __restrict__ bias, ushort_t* __restrict__ outB, int ldo,
    float* __restrict__ outF, const float* __restrict__ ao,
    const float* __restrict__ aff) {
    __shared__ __align__(16) ushort_t xs[64][72];
    __shared__ __align__(16) ushort_t wt[64][72];
    int col0 = blockIdx.x * 64;
    int row0 = blockIdx.y * 64;
    int u = (row0 >> 9) & 7;
    const ushort_t* Wu = WT + ((size_t)u * wPerU + col0) * 256;
    int tid = threadIdx.x;
    int w = tid >> 6, l = tid & 63;
    int lr = l & 15, lg = l >> 4;
    f32x4 acc[4] = {};
    for (int k0 = 0; k0 < 256; k0 += 64) {
        int r1 = tid >> 3, ko1 = (tid & 7) * 8;
        int r2 = (tid + 256) >> 3, ko2 = ((tid + 256) & 7) * 8;
        *(bf16x8*)&xs[r1][ko1] = *(const bf16x8*)&X[(size_t)(row0 + r1) * 256 + k0 + ko1];
        *(bf16x8*)&xs[r2][ko2] = *(const bf16x8*)&X[(size_t)(row0 + r2) * 256 + k0 + ko2];
        *(bf16x8*)&wt[r1][ko1] = *(const bf16x8*)&Wu[(size_t)r1 * 256 + k0 + ko1];
        *(bf16x8*)&wt[r2][ko2] = *(const bf16x8*)&Wu[(size_t)r2 * 256 + k0 + ko2];
        __syncthreads();
        #pragma unroll
        for (int n = 0; n < 4; ++n) {
            #pragma unroll
            for (int kk = 0; kk < 2; ++kk) {
                bf16x8 a = *(const bf16x8*)&xs[w * 16 + lr][kk * 32 + lg * 8];
                bf16x8 bb = *(const bf16x8*)&wt[n * 16 + lr][kk * 32 + lg * 8];
                acc[n] = __builtin_amdgcn_mfma_f32_16x16x32_bf16(a, bb, acc[n], 0, 0, 0);
            }
        }
        __syncthreads();
    }
    #pragma unroll
    for (int n = 0; n < 4; ++n) {
        int col = col0 + n * 16 + lr;
        float bval = bias[col];
        #pragma unroll
        for (int i = 0; i < 4; ++i) {
            int row = row0 + w * 16 + lg * 4 + i;
            float v = gelu_exact(acc[n][i] + bval);
            if (MODE == 2) {
                float a = aff[row];
                float aov = ao[(size_t)row * 256 + col];
                outF[(size_t)row * 256 + col] = (1.f - a) * aov + GAIN_ * a * a * v;
            } else {
                outB[(size_t)row * ldo + col] = f2bf(v);
            }
        }
    }
}

extern "C" void kernel_launch(void* const* d_in, const int* in_sizes, int n_in,
                              void* d_out, int out_size, void* d_ws, size_t ws_size,
                              hipStream_t stream) {
    const float* variables  = (const float*)d_in[0];
    const float* codes      = (const float*)d_in[1];
    const float* affinities = (const float*)d_in[2];
    const float* ln1_g = (const float*)d_in[3];
    const float* ln1_b = (const float*)d_in[4];
    const float* Wq  = (const float*)d_in[5];
    const float* Wcq = (const float*)d_in[6];
    const float* Wk  = (const float*)d_in[7];
    const float* Wck = (const float*)d_in[8];
    const float* Wv  = (const float*)d_in[9];
    const float* Wcv = (const float*)d_in[10];
    const float* bv  = (const float*)d_in[11];
    const float* ln2_g = (const float*)d_in[12];
    const float* ln2_b = (const float*)d_in[13];
    const float* W1  = (const float*)d_in[14];
    const float* Wc1 = (const float*)d_in[15];
    const float* b1m = (const float*)d_in[16];
    const float* W2  = (const float*)d_in[17];
    const float* Wc2 = (const float*)d_in[18];
    const float* b2m = (const float*)d_in[19];

    char* p = (char*)d_ws;
    float* modsF = (float*)p;   p += 40960;        // [5][8][256] f32
    float* biasQ = (float*)p;   p += 5120;         // [1280] f32
    float* attF  = (float*)p;   p += 8388608;      // [8192][256] f32
    float* aoF   = (float*)p;   p += 8388608;      // [8192][256] f32
    ushort_t* xnb   = (ushort_t*)p; p += 4194304;  // [8192][256] bf16
    ushort_t* wqkvT = (ushort_t*)p; p += 5242880;  // [8][1280][256] bf16
    ushort_t* w1T   = (ushort_t*)p; p += 1048576;  // [8][256][256] bf16
    ushort_t* w2T   = (ushort_t*)p; p += 1048576;  // [8][256][256] bf16
    ushort_t* qkvb  = (ushort_t*)p; p += 20971520; // [8192][1280] bf16
    ushort_t* ynb   = (ushort_t*)p; p += 4194304;  // [8192][256] bf16
    ushort_t* h1b   = (ushort_t*)p; p += 4194304;  // [8192][256] bf16
    ushort_t* vTb   = (ushort_t*)p; p += 4194304;  // [16*8][32][512] bf16
    float* outp = (float*)d_out;

    k_mods<<<40, 256, 0, stream>>>(codes, Wcq, Wck, Wcv, Wc1, Wc2, bv, modsF, biasQ);
    k_fold<<<896, 256, 0, stream>>>(Wq, Wk, Wv, W1, W2, modsF, wqkvT, w1T, w2T);
    k_ln1<<<2048, 256, 0, stream>>>(variables, ln1_g, ln1_b, xnb);
    k_qkv<<<dim3(10, 64), 256, 0, stream>>>(xnb, wqkvT, biasQ, qkvb, vTb);
    k_attn<<<1024, 256, 0, stream>>>(qkvb, vTb, affinities, attF);
    k_gate_ln2<<<2048, 256, 0, stream>>>(variables, attF, affinities, ln2_g, ln2_b, aoF, ynb);
    k_gemm<1><<<dim3(4, 128), 256, 0, stream>>>(ynb, w1T, 256, b1m, h1b, 256,
                                                nullptr, nullptr, nullptr);
    k_gemm<2><<<dim3(4, 128), 256, 0, stream>>>(h1b, w2T, 256, b2m, nullptr, 256,
                                                outp, aoF, affinities);
}

// Round 7
// 166.772 us; speedup vs baseline: 2.4240x; 1.0529x over previous
//
#include <hip/hip_runtime.h>
#include <math.h>

#define B_ 2
#define U_ 8
#define V_ 512
#define C_ 256
#define H_ 8
#define R_ 256
#define EPS_ 1e-6f
#define LN_EPS_ 1e-5f
#define GAIN_ 2.5f

typedef __attribute__((ext_vector_type(8))) short bf16x8;
typedef __attribute__((ext_vector_type(4))) float f32x4;
typedef unsigned short ushort_t;

__device__ __forceinline__ ushort_t f2bf(float x) {
    union { float f; unsigned u; } v; v.f = x;
    unsigned r = v.u + 0x7fffu + ((v.u >> 16) & 1u);
    return (ushort_t)(r >> 16);
}

__device__ __forceinline__ float waveReduceSum(float v) {
    #pragma unroll
    for (int m = 1; m < 64; m <<= 1) v += __shfl_xor(v, m);
    return v;
}

__device__ __forceinline__ float gelu_exact(float x) {
    return 0.5f * x * (1.f + erff(x * 0.70710678118654752f));
}

// Fused prep: blocks [0,896) fold weights (with inline modulation dots);
// blocks [896,2944) LayerNorm1 (4 rows each).
// Fold: out = bf16( W[c][col] * (1 + codes_u . Wc[:,c]) ), stored TRANSPOSED [u][col][c].
__global__ __launch_bounds__(256) void k_prep(
    const float* __restrict__ codes,
    const float* __restrict__ Wcq, const float* __restrict__ Wck,
    const float* __restrict__ Wcv, const float* __restrict__ Wc1,
    const float* __restrict__ Wc2,
    const float* __restrict__ Wq, const float* __restrict__ Wk,
    const float* __restrict__ Wv, const float* __restrict__ W1,
    const float* __restrict__ W2,
    const float* __restrict__ x, const float* __restrict__ ln1g,
    const float* __restrict__ ln1b,
    ushort_t* __restrict__ wqkvT, ushort_t* __restrict__ w1T,
    ushort_t* __restrict__ w2T, ushort_t* __restrict__ xnb) {
    int bid = blockIdx.x;
    int tid = threadIdx.x;
    if (bid >= 896) {
        // ----- LayerNorm1 -> bf16 -----
        int row = (bid - 896) * 4 + (tid >> 6);
        int lane = tid & 63;
        const float* xr = x + (size_t)row * C_;
        float4 v = *(const float4*)&xr[lane * 4];
        float s = v.x + v.y + v.z + v.w;
        float ss = v.x * v.x + v.y * v.y + v.z * v.z + v.w * v.w;
        s = waveReduceSum(s); ss = waveReduceSum(ss);
        float mean = s * (1.f / 256.f);
        float var = ss * (1.f / 256.f) - mean * mean;
        float rstd = rsqrtf(var + LN_EPS_);
        float4 gg = *(const float4*)&ln1g[lane * 4];
        float4 bb = *(const float4*)&ln1b[lane * 4];
        unsigned lo = (unsigned)f2bf((v.x - mean) * rstd * gg.x + bb.x)
                    | ((unsigned)f2bf((v.y - mean) * rstd * gg.y + bb.y) << 16);
        unsigned hi = (unsigned)f2bf((v.z - mean) * rstd * gg.z + bb.z)
                    | ((unsigned)f2bf((v.w - mean) * rstd * gg.w + bb.w) << 16);
        uint2 pk; pk.x = lo; pk.y = hi;
        *(uint2*)&xnb[(size_t)row * C_ + lane * 4] = pk;
        return;
    }
    // ----- fold path -----
    __shared__ float mpart[4][64];
    __shared__ float mrow[64];
    __shared__ ushort_t T[64][65];
    int id = bid;
    const float* W; int ldw, modIdx, colAdd, tilesPerU, base;
    ushort_t* dst; int dstCols;
    if (id < 256)      { base = 0;   W = Wq; ldw = 512; modIdx = 0; colAdd = 0;    dst = wqkvT; dstCols = 1280; tilesPerU = 32; }
    else if (id < 512) { base = 256; W = Wk; ldw = 512; modIdx = 1; colAdd = 512;  dst = wqkvT; dstCols = 1280; tilesPerU = 32; }
    else if (id < 640) { base = 512; W = Wv; ldw = 256; modIdx = 2; colAdd = 1024; dst = wqkvT; dstCols = 1280; tilesPerU = 16; }
    else if (id < 768) { base = 640; W = W1; ldw = 256; modIdx = 3; colAdd = 0;    dst = w1T;  dstCols = 256;  tilesPerU = 16; }
    else               { base = 768; W = W2; ldw = 256; modIdx = 4; colAdd = 0;    dst = w2T;  dstCols = 256;  tilesPerU = 16; }
    const float* Wc = (modIdx == 0) ? Wcq : (modIdx == 1) ? Wck :
                      (modIdx == 2) ? Wcv : (modIdx == 3) ? Wc1 : Wc2;
    int local = id - base;
    int u = local / tilesPerU;
    int t = local % tilesPerU;
    int nColTiles = ldw / 64;
    int c0 = (t / nColTiles) * 64;
    int col0 = (t % nColTiles) * 64;
    // inline mods for input-dims c0..c0+63: 1 + codes_u . Wc[:, c]
    {
        const float* cd = codes + u * 192;
        int cc = tid & 63, g = tid >> 6;
        float accm = 0.f;
        #pragma unroll 4
        for (int jj = 0; jj < 48; ++jj) {
            int j = g * 48 + jj;
            accm = fmaf(cd[j], Wc[j * 256 + c0 + cc], accm);
        }
        mpart[g][cc] = accm;
        __syncthreads();
        if (tid < 64)
            mrow[tid] = 1.f + mpart[0][tid] + mpart[1][tid] + mpart[2][tid] + mpart[3][tid];
        __syncthreads();
    }
    int cl = tid >> 4;
    int cg = (tid & 15) * 4;
    #pragma unroll
    for (int it = 0; it < 4; ++it) {
        int c = cl + it * 16;
        float m = mrow[c];
        float4 wv = *(const float4*)&W[(size_t)(c0 + c) * ldw + col0 + cg];
        T[c][cg + 0] = f2bf(wv.x * m);
        T[c][cg + 1] = f2bf(wv.y * m);
        T[c][cg + 2] = f2bf(wv.z * m);
        T[c][cg + 3] = f2bf(wv.w * m);
    }
    __syncthreads();
    int j = tid >> 2;
    int ch = (tid & 3) * 16;
    ushort_t tmp[16];
    #pragma unroll
    for (int i = 0; i < 16; ++i) tmp[i] = T[ch + i][j];
    ushort_t* o = dst + ((size_t)u * dstCols + colAdd + col0 + j) * 256 + c0 + ch;
    *(bf16x8*)&o[0] = *(const bf16x8*)&tmp[0];
    *(bf16x8*)&o[8] = *(const bf16x8*)&tmp[8];
}

// QKV GEMM, 128x128 tiles, 4 waves in 2x2 quadrants, K-step 64.
// out = qkv [8192][1280] bf16; V region also written transposed to vT[bu*8+h][c][s].
__global__ __launch_bounds__(256) void k_qkv(
    const ushort_t* __restrict__ X, const ushort_t* __restrict__ WT,
    const float* __restrict__ bv, ushort_t* __restrict__ out,
    ushort_t* __restrict__ vT) {
    __shared__ __align__(16) ushort_t xs[128][72];
    __shared__ __align__(16) ushort_t wt[128][72];
    int col0 = blockIdx.x * 128;
    int row0 = blockIdx.y * 128;
    int u = (row0 >> 9) & 7;
    const ushort_t* Wu = WT + (size_t)(u * 1280 + col0) * 256;
    int tid = threadIdx.x;
    int w = tid >> 6, l = tid & 63;
    int lr = l & 15, lg = l >> 4;
    int wm = w >> 1, wn = w & 1;
    f32x4 acc[4][4] = {};
    int sr = tid >> 3, sko = (tid & 7) * 8;
    for (int k0 = 0; k0 < 256; k0 += 64) {
        #pragma unroll
        for (int it = 0; it < 4; ++it) {
            int r = sr + it * 32;
            *(bf16x8*)&xs[r][sko] = *(const bf16x8*)&X[(size_t)(row0 + r) * 256 + k0 + sko];
            *(bf16x8*)&wt[r][sko] = *(const bf16x8*)&Wu[(size_t)r * 256 + k0 + sko];
        }
        __syncthreads();
        #pragma unroll
        for (int m = 0; m < 4; ++m) {
            #pragma unroll
            for (int kk = 0; kk < 2; ++kk) {
                bf16x8 a = *(const bf16x8*)&xs[wm * 64 + m * 16 + lr][kk * 32 + lg * 8];
                #pragma unroll
                for (int n = 0; n < 4; ++n) {
                    bf16x8 bb = *(const bf16x8*)&wt[wn * 64 + n * 16 + lr][kk * 32 + lg * 8];
                    acc[m][n] = __builtin_amdgcn_mfma_f32_16x16x32_bf16(a, bb, acc[m][n], 0, 0, 0);
                }
            }
        }
        __syncthreads();
    }
    #pragma unroll
    for (int m = 0; m < 4; ++m) {
        int rowb = row0 + wm * 64 + m * 16 + lg * 4;
        #pragma unroll
        for (int n = 0; n < 4; ++n) {
            int col = col0 + wn * 64 + n * 16 + lr;
            float bval = (col >= 1024) ? bv[col - 1024] : 0.f;
            ushort_t pk4[4];
            #pragma unroll
            for (int i = 0; i < 4; ++i) {
                float v = acc[m][n][i] + bval;
                pk4[i] = f2bf(v);
                out[(size_t)(rowb + i) * 1280 + col] = pk4[i];
            }
            if (col >= 1024) {   // V: also store transposed [bu*8+h][c][s]
                int hh = (col - 1024) >> 5, cc = (col - 1024) & 31;
                int bu = rowb >> 9;
                uint2 pw;
                pw.x = (unsigned)pk4[0] | ((unsigned)pk4[1] << 16);
                pw.y = (unsigned)pk4[2] | ((unsigned)pk4[3] << 16);
                *(uint2*)&vT[(size_t)((bu * 8 + hh) * 32 + cc) * 512 + (rowb & 511)] = pw;
            }
        }
    }
}

// Attention per (bu,h,64-row tile). Swapped QK^T (mfma(K,Q)); register prefetch (T14);
// XCD-aware swizzle keeps each bu's K/V slice on one XCD's L2.
__global__ __launch_bounds__(256) void k_attn(
    const ushort_t* __restrict__ qkv, const ushort_t* __restrict__ vT,
    const float* __restrict__ aff, float* __restrict__ att) {
    __shared__ __align__(16) ushort_t Qs[64][72];
    __shared__ __align__(16) ushort_t Ks[64][72];
    __shared__ __align__(16) ushort_t Pt[64][72];
    __shared__ __align__(16) ushort_t Vt[32][72];
    __shared__ float As[64];
    int id = blockIdx.x;
    int xcd = id & 7, sl = id >> 3;
    int bu = xcd + 8 * (sl >> 6);
    int inr = sl & 63;
    int h = inr & 7;
    int r0 = (inr >> 3) * 64;
    const ushort_t* base = qkv + (size_t)bu * 512 * 1280;
    const ushort_t* vbase = vT + (size_t)((bu * 8 + h) * 32) * 512;
    int tid = threadIdx.x;
    int w = tid >> 6, l = tid & 63;
    int lr = l & 15, lg = l >> 4;
    int sr = tid >> 3, sko = (tid & 7) * 8;
    *(bf16x8*)&Qs[sr][sko]      = *(const bf16x8*)&base[(size_t)(r0 + sr) * 1280 + h * 64 + sko];
    *(bf16x8*)&Qs[sr + 32][sko] = *(const bf16x8*)&base[(size_t)(r0 + sr + 32) * 1280 + h * 64 + sko];
    bf16x8 kr0 = *(const bf16x8*)&base[(size_t)sr * 1280 + 512 + h * 64 + sko];
    bf16x8 kr1 = *(const bf16x8*)&base[(size_t)(sr + 32) * 1280 + 512 + h * 64 + sko];
    bf16x8 vr  = *(const bf16x8*)&vbase[(size_t)sr * 512 + sko];
    float afv = (tid < 64) ? aff[bu * 512 + tid] : 0.f;
    *(bf16x8*)&Ks[sr][sko] = kr0;
    *(bf16x8*)&Ks[sr + 32][sko] = kr1;
    if (sr < 32) *(bf16x8*)&Vt[sr][sko] = vr;
    if (tid < 64) As[tid] = afv;
    __syncthreads();
    float wsum = 0.f, asum = 0.f;
    f32x4 pacc[2] = {};
    for (int t = 0; t < 8; ++t) {
        int s0n = (t + 1) * 64;
        if (t < 7) {
            kr0 = *(const bf16x8*)&base[(size_t)(s0n + sr) * 1280 + 512 + h * 64 + sko];
            kr1 = *(const bf16x8*)&base[(size_t)(s0n + sr + 32) * 1280 + 512 + h * 64 + sko];
            if (sr < 32) vr = *(const bf16x8*)&vbase[(size_t)sr * 512 + s0n + sko];
            if (tid < 64) afv = aff[bu * 512 + s0n + tid];
        }
        #pragma unroll
        for (int n = 0; n < 4; ++n) {
            f32x4 sc = {};
            #pragma unroll
            for (int kk = 0; kk < 2; ++kk) {
                bf16x8 ka = *(const bf16x8*)&Ks[n * 16 + lr][kk * 32 + lg * 8];
                bf16x8 qb = *(const bf16x8*)&Qs[w * 16 + lr][kk * 32 + lg * 8];
                sc = __builtin_amdgcn_mfma_f32_16x16x32_bf16(ka, qb, sc, 0, 0, 0);
            }
            float4 a4 = *(const float4*)&As[n * 16 + lg * 4];
            float e0 = __expf(sc[0]), e1 = __expf(sc[1]);
            float e2 = __expf(sc[2]), e3 = __expf(sc[3]);
            wsum += (e0 + e1) + (e2 + e3);
            float ae0 = e0 * a4.x, ae1 = e1 * a4.y, ae2 = e2 * a4.z, ae3 = e3 * a4.w;
            asum += (ae0 + ae1) + (ae2 + ae3);
            uint2 pw;
            pw.x = (unsigned)f2bf(ae0) | ((unsigned)f2bf(ae1) << 16);
            pw.y = (unsigned)f2bf(ae2) | ((unsigned)f2bf(ae3) << 16);
            *(uint2*)&Pt[w * 16 + lr][n * 16 + lg * 4] = pw;
        }
        #pragma unroll
        for (int n = 0; n < 2; ++n) {
            #pragma unroll
            for (int kk = 0; kk < 2; ++kk) {
                bf16x8 pa = *(const bf16x8*)&Pt[w * 16 + lr][kk * 32 + lg * 8];
                bf16x8 vb = *(const bf16x8*)&Vt[n * 16 + lr][kk * 32 + lg * 8];
                pacc[n] = __builtin_amdgcn_mfma_f32_16x16x32_bf16(pa, vb, pacc[n], 0, 0, 0);
            }
        }
        __syncthreads();
        if (t < 7) {
            *(bf16x8*)&Ks[sr][sko] = kr0;
            *(bf16x8*)&Ks[sr + 32][sko] = kr1;
            if (sr < 32) *(bf16x8*)&Vt[sr][sko] = vr;
            if (tid < 64) As[tid] = afv;
            __syncthreads();
        }
    }
    asum += __shfl_xor(asum, 16); asum += __shfl_xor(asum, 32);
    wsum += __shfl_xor(wsum, 16); wsum += __shfl_xor(wsum, 32);
    float ar = aff[bu * 512 + r0 + w * 16 + lr];
    float scale = ar / (ar * asum + EPS_ * wsum);
    #pragma unroll
    for (int i = 0; i < 4; ++i) {
        float sc_i = __shfl(scale, lg * 4 + i);
        int q = r0 + w * 16 + lg * 4 + i;
        float* ob = att + ((size_t)bu * 512 + q) * 256 + h * 32;
        ob[lr]      = pacc[0][i] * sc_i;
        ob[16 + lr] = pacc[1][i] * sc_i;
    }
}

// Fused tail: ao = (1-a)x + aG*att; yn = LN2(ao); h1 = gelu(ModLin1(yn));
// h2 = gelu(ModLin2(h1)); out = (1-a)ao + G a^2 h2.
// 32 rows/block, MLPs computed transposed (A = W^T staged in LDS, B = activations
// row-major) so each lane owns 4 consecutive output channels at a fixed token row.
// ao is never materialized: recomputed from x/att in the epilogue (L2-hot).
__global__ __launch_bounds__(256) void k_tail(
    const float* __restrict__ x, const float* __restrict__ att,
    const float* __restrict__ aff, const float* __restrict__ g2,
    const float* __restrict__ b2, const ushort_t* __restrict__ w1T,
    const ushort_t* __restrict__ w2T, const float* __restrict__ b1m,
    const float* __restrict__ b2m, float* __restrict__ outp) {
    __shared__ __align__(16) ushort_t yn[32][264];   // reused as h1
    __shared__ __align__(16) ushort_t wt[256][72];
    int r0 = blockIdx.x * 32;
    int u = (r0 >> 9) & 7;
    int tid = threadIdx.x;
    // ---- phase 1: gate + LN2 -> yn (bf16, LDS) ----
    {
        int row = tid >> 3, cb = (tid & 7) * 32;
        float a = aff[r0 + row];
        const float* xr = x + (size_t)(r0 + row) * 256 + cb;
        const float* ar = att + (size_t)(r0 + row) * 256 + cb;
        float4 o[8];
        float s = 0.f, ss = 0.f;
        #pragma unroll
        for (int j = 0; j < 8; ++j) {
            float4 xv = *(const float4*)&xr[j * 4];
            float4 av = *(const float4*)&ar[j * 4];
            float4 t;
            t.x = (1.f - a) * xv.x + a * GAIN_ * av.x;
            t.y = (1.f - a) * xv.y + a * GAIN_ * av.y;
            t.z = (1.f - a) * xv.z + a * GAIN_ * av.z;
            t.w = (1.f - a) * xv.w + a * GAIN_ * av.w;
            o[j] = t;
            s += (t.x + t.y) + (t.z + t.w);
            ss += (t.x * t.x + t.y * t.y) + (t.z * t.z + t.w * t.w);
        }
        s += __shfl_xor(s, 1); s += __shfl_xor(s, 2); s += __shfl_xor(s, 4);
        ss += __shfl_xor(ss, 1); ss += __shfl_xor(ss, 2); ss += __shfl_xor(ss, 4);
        float mean = s * (1.f / 256.f);
        float var = ss * (1.f / 256.f) - mean * mean;
        float rstd = rsqrtf(var + LN_EPS_);
        #pragma unroll
        for (int j = 0; j < 8; ++j) {
            float4 gg = *(const float4*)&g2[cb + j * 4];
            float4 bb = *(const float4*)&b2[cb + j * 4];
            uint2 pk;
            pk.x = (unsigned)f2bf((o[j].x - mean) * rstd * gg.x + bb.x)
                 | ((unsigned)f2bf((o[j].y - mean) * rstd * gg.y + bb.y) << 16);
            pk.y = (unsigned)f2bf((o[j].z - mean) * rstd * gg.z + bb.z)
                 | ((unsigned)f2bf((o[j].w - mean) * rstd * gg.w + bb.w) << 16);
            *(uint2*)&yn[row][cb + j * 4] = pk;
        }
    }
    __syncthreads();
    int w = tid >> 6, l = tid & 63, lr = l & 15, lg = l >> 4;
    int tokT = w & 1, nh = w >> 1;
    int scol = tid >> 3, sko = (tid & 7) * 8;
    const ushort_t* W1u = w1T + (size_t)u * 256 * 256;
    const ushort_t* W2u = w2T + (size_t)u * 256 * 256;
    // ---- MLP1 (transposed): out1^T[n'][tok] ----
    f32x4 acc[8] = {};
    for (int k0 = 0; k0 < 256; k0 += 64) {
        #pragma unroll
        for (int it = 0; it < 8; ++it)
            *(bf16x8*)&wt[scol + it * 32][sko] =
                *(const bf16x8*)&W1u[(size_t)(scol + it * 32) * 256 + k0 + sko];
        __syncthreads();
        #pragma unroll
        for (int n = 0; n < 8; ++n) {
            #pragma unroll
            for (int kk = 0; kk < 2; ++kk) {
                bf16x8 a = *(const bf16x8*)&wt[(nh * 8 + n) * 16 + lr][kk * 32 + lg * 8];
                bf16x8 b = *(const bf16x8*)&yn[tokT * 16 + lr][k0 + kk * 32 + lg * 8];
                acc[n] = __builtin_amdgcn_mfma_f32_16x16x32_bf16(a, b, acc[n], 0, 0, 0);
            }
        }
        __syncthreads();
    }
    // h1 = gelu(out1 + b1) -> overwrite yn (each wave writes only its own token rows)
    #pragma unroll
    for (int n = 0; n < 8; ++n) {
        int nc = (nh * 8 + n) * 16 + lg * 4;
        float4 bv1 = *(const float4*)&b1m[nc];
        ushort_t p0 = f2bf(gelu_exact(acc[n][0] + bv1.x));
        ushort_t p1 = f2bf(gelu_exact(acc[n][1] + bv1.y));
        ushort_t p2 = f2bf(gelu_exact(acc[n][2] + bv1.z));
        ushort_t p3 = f2bf(gelu_exact(acc[n][3] + bv1.w));
        uint2 pw;
        pw.x = (unsigned)p0 | ((unsigned)p1 << 16);
        pw.y = (unsigned)p2 | ((unsigned)p3 << 16);
        *(uint2*)&yn[tokT * 16 + lr][nc] = pw;
    }
    // ---- MLP2 (transposed) ----
    f32x4 acc2[8] = {};
    for (int k0 = 0; k0 < 256; k0 += 64) {
        #pragma unroll
        for (int it = 0; it < 8; ++it)
            *(bf16x8*)&wt[scol + it * 32][sko] =
                *(const bf16x8*)&W2u[(size_t)(scol + it * 32) * 256 + k0 + sko];
        __syncthreads();
        #pragma unroll
        for (int n = 0; n < 8; ++n) {
            #pragma unroll
            for (int kk = 0; kk < 2; ++kk) {
                bf16x8 a = *(const bf16x8*)&wt[(nh * 8 + n) * 16 + lr][kk * 32 + lg * 8];
                bf16x8 b = *(const bf16x8*)&yn[tokT * 16 + lr][k0 + kk * 32 + lg * 8];
                acc2[n] = __builtin_amdgcn_mfma_f32_16x16x32_bf16(a, b, acc2[n], 0, 0, 0);
            }
        }
        __syncthreads();
    }
    // ---- epilogue: gelu + final gating (ao recomputed), float4 stores ----
    int orow = r0 + tokT * 16 + lr;
    float a = aff[orow];
    #pragma unroll
    for (int n = 0; n < 8; ++n) {
        int nc = (nh * 8 + n) * 16 + lg * 4;
        float4 bv2 = *(const float4*)&b2m[nc];
        float4 xv = *(const float4*)&x[(size_t)orow * 256 + nc];
        float4 av = *(const float4*)&att[(size_t)orow * 256 + nc];
        float4 r;
        {
            float h2 = gelu_exact(acc2[n][0] + bv2.x);
            float ao = (1.f - a) * xv.x + a * GAIN_ * av.x;
            r.x = (1.f - a) * ao + GAIN_ * a * a * h2;
        }
        {
            float h2 = gelu_exact(acc2[n][1] + bv2.y);
            float ao = (1.f - a) * xv.y + a * GAIN_ * av.y;
            r.y = (1.f - a) * ao + GAIN_ * a * a * h2;
        }
        {
            float h2 = gelu_exact(acc2[n][2] + bv2.z);
            float ao = (1.f - a) * xv.z + a * GAIN_ * av.z;
            r.z = (1.f - a) * ao + GAIN_ * a * a * h2;
        }
        {
            float h2 = gelu_exact(acc2[n][3] + bv2.w);
            float ao = (1.f - a) * xv.w + a * GAIN_ * av.w;
            r.w = (1.f - a) * ao + GAIN_ * a * a * h2;
        }
        *(float4*)&outp[(size_t)orow * 256 + nc] = r;
    }
}

extern "C" void kernel_launch(void* const* d_in, const int* in_sizes, int n_in,
                              void* d_out, int out_size, void* d_ws, size_t ws_size,
                              hipStream_t stream) {
    const float* variables  = (const float*)d_in[0];
    const float* codes      = (const float*)d_in[1];
    const float* affinities = (const float*)d_in[2];
    const float* ln1_g = (const float*)d_in[3];
    const float* ln1_b = (const float*)d_in[4];
    const float* Wq  = (const float*)d_in[5];
    const float* Wcq = (const float*)d_in[6];
    const float* Wk  = (const float*)d_in[7];
    const float* Wck = (const float*)d_in[8];
    const float* Wv  = (const float*)d_in[9];
    const float* Wcv = (const float*)d_in[10];
    const float* bv  = (const float*)d_in[11];
    const float* ln2_g = (const float*)d_in[12];
    const float* ln2_b = (const float*)d_in[13];
    const float* W1  = (const float*)d_in[14];
    const float* Wc1 = (const float*)d_in[15];
    const float* b1m = (const float*)d_in[16];
    const float* W2  = (const float*)d_in[17];
    const float* Wc2 = (const float*)d_in[18];
    const float* b2m = (const float*)d_in[19];

    char* p = (char*)d_ws;
    float* attF     = (float*)p;    p += 8388608;   // [8192][256] f32
    ushort_t* xnb   = (ushort_t*)p; p += 4194304;   // [8192][256] bf16
    ushort_t* wqkvT = (ushort_t*)p; p += 5242880;   // [8][1280][256] bf16
    ushort_t* w1T   = (ushort_t*)p; p += 1048576;   // [8][256][256] bf16
    ushort_t* w2T   = (ushort_t*)p; p += 1048576;   // [8][256][256] bf16
    ushort_t* qkvb  = (ushort_t*)p; p += 20971520;  // [8192][1280] bf16
    ushort_t* vTb   = (ushort_t*)p; p += 4194304;   // [16*8][32][512] bf16
    float* outp = (float*)d_out;

    k_prep<<<2944, 256, 0, stream>>>(codes, Wcq, Wck, Wcv, Wc1, Wc2,
                                     Wq, Wk, Wv, W1, W2,
                                     variables, ln1_g, ln1_b,
                                     wqkvT, w1T, w2T, xnb);
    k_qkv<<<dim3(10, 64), 256, 0, stream>>>(xnb, wqkvT, bv, qkvb, vTb);
    k_attn<<<1024, 256, 0, stream>>>(qkvb, vTb, affinities, attF);
    k_tail<<<256, 256, 0, stream>>>(variables, attF, affinities, ln2_g, ln2_b,
                                    w1T, w2T, b1m, b2m, outp);
}

// Round 12
// 150.933 us; speedup vs baseline: 2.6783x; 1.1049x over previous
//
#include <hip/hip_runtime.h>
#include <math.h>

#define B_ 2
#define U_ 8
#define V_ 512
#define C_ 256
#define H_ 8
#define R_ 256
#define EPS_ 1e-6f
#define LN_EPS_ 1e-5f
#define GAIN_ 2.5f

typedef __attribute__((ext_vector_type(8))) short bf16x8;
typedef __attribute__((ext_vector_type(4))) float f32x4;
typedef unsigned short ushort_t;

__device__ __forceinline__ ushort_t f2bf(float x) {
    union { float f; unsigned u; } v; v.f = x;
    unsigned r = v.u + 0x7fffu + ((v.u >> 16) & 1u);
    return (ushort_t)(r >> 16);
}

__device__ __forceinline__ float bf2f(ushort_t h) {
    union { unsigned u; float f; } v; v.u = (unsigned)h << 16; return v.f;
}

__device__ __forceinline__ unsigned cvt_pk_bf16(float lo, float hi) {
    unsigned r;
    asm("v_cvt_pk_bf16_f32 %0, %1, %2" : "=v"(r) : "v"(lo), "v"(hi));
    return r;
}

__device__ __forceinline__ float waveReduceSum(float v) {
    #pragma unroll
    for (int m = 1; m < 64; m <<= 1) v += __shfl_xor(v, m);
    return v;
}

__device__ __forceinline__ float gelu_exact(float x) {
    return 0.5f * x * (1.f + erff(x * 0.70710678118654752f));
}

// Fused prep: blocks [0,896) fold weights (with inline modulation dots);
// blocks [896,2944) LayerNorm1 (4 rows each).
__global__ __launch_bounds__(256) void k_prep(
    const float* __restrict__ codes,
    const float* __restrict__ Wcq, const float* __restrict__ Wck,
    const float* __restrict__ Wcv, const float* __restrict__ Wc1,
    const float* __restrict__ Wc2,
    const float* __restrict__ Wq, const float* __restrict__ Wk,
    const float* __restrict__ Wv, const float* __restrict__ W1,
    const float* __restrict__ W2,
    const float* __restrict__ x, const float* __restrict__ ln1g,
    const float* __restrict__ ln1b,
    ushort_t* __restrict__ wqkvT, ushort_t* __restrict__ w1T,
    ushort_t* __restrict__ w2T, ushort_t* __restrict__ xnb) {
    int bid = blockIdx.x;
    int tid = threadIdx.x;
    if (bid >= 896) {
        int row = (bid - 896) * 4 + (tid >> 6);
        int lane = tid & 63;
        const float* xr = x + (size_t)row * C_;
        float4 v = *(const float4*)&xr[lane * 4];
        float s = v.x + v.y + v.z + v.w;
        float ss = v.x * v.x + v.y * v.y + v.z * v.z + v.w * v.w;
        s = waveReduceSum(s); ss = waveReduceSum(ss);
        float mean = s * (1.f / 256.f);
        float var = ss * (1.f / 256.f) - mean * mean;
        float rstd = rsqrtf(var + LN_EPS_);
        float4 gg = *(const float4*)&ln1g[lane * 4];
        float4 bb = *(const float4*)&ln1b[lane * 4];
        uint2 pk;
        pk.x = (unsigned)f2bf((v.x - mean) * rstd * gg.x + bb.x)
             | ((unsigned)f2bf((v.y - mean) * rstd * gg.y + bb.y) << 16);
        pk.y = (unsigned)f2bf((v.z - mean) * rstd * gg.z + bb.z)
             | ((unsigned)f2bf((v.w - mean) * rstd * gg.w + bb.w) << 16);
        *(uint2*)&xnb[(size_t)row * C_ + lane * 4] = pk;
        return;
    }
    __shared__ float mpart[4][64];
    __shared__ float mrow[64];
    __shared__ ushort_t T[64][65];
    int id = bid;
    const float* W; int ldw, modIdx, colAdd, tilesPerU, base;
    ushort_t* dst; int dstCols;
    if (id < 256)      { base = 0;   W = Wq; ldw = 512; modIdx = 0; colAdd = 0;    dst = wqkvT; dstCols = 1280; tilesPerU = 32; }
    else if (id < 512) { base = 256; W = Wk; ldw = 512; modIdx = 1; colAdd = 512;  dst = wqkvT; dstCols = 1280; tilesPerU = 32; }
    else if (id < 640) { base = 512; W = Wv; ldw = 256; modIdx = 2; colAdd = 1024; dst = wqkvT; dstCols = 1280; tilesPerU = 16; }
    else if (id < 768) { base = 640; W = W1; ldw = 256; modIdx = 3; colAdd = 0;    dst = w1T;  dstCols = 256;  tilesPerU = 16; }
    else               { base = 768; W = W2; ldw = 256; modIdx = 4; colAdd = 0;    dst = w2T;  dstCols = 256;  tilesPerU = 16; }
    const float* Wc = (modIdx == 0) ? Wcq : (modIdx == 1) ? Wck :
                      (modIdx == 2) ? Wcv : (modIdx == 3) ? Wc1 : Wc2;
    int local = id - base;
    int u = local / tilesPerU;
    int t = local % tilesPerU;
    int nColTiles = ldw / 64;
    int c0 = (t / nColTiles) * 64;
    int col0 = (t % nColTiles) * 64;
    {
        const float* cd = codes + u * 192;
        int cc = tid & 63, g = tid >> 6;
        float accm = 0.f;
        #pragma unroll 4
        for (int jj = 0; jj < 48; ++jj) {
            int j = g * 48 + jj;
            accm = fmaf(cd[j], Wc[j * 256 + c0 + cc], accm);
        }
        mpart[g][cc] = accm;
        __syncthreads();
        if (tid < 64)
            mrow[tid] = 1.f + mpart[0][tid] + mpart[1][tid] + mpart[2][tid] + mpart[3][tid];
        __syncthreads();
    }
    int cl = tid >> 4;
    int cg = (tid & 15) * 4;
    #pragma unroll
    for (int it = 0; it < 4; ++it) {
        int c = cl + it * 16;
        float m = mrow[c];
        float4 wv = *(const float4*)&W[(size_t)(c0 + c) * ldw + col0 + cg];
        T[c][cg + 0] = f2bf(wv.x * m);
        T[c][cg + 1] = f2bf(wv.y * m);
        T[c][cg + 2] = f2bf(wv.z * m);
        T[c][cg + 3] = f2bf(wv.w * m);
    }
    __syncthreads();
    int j = tid >> 2;
    int ch = (tid & 3) * 16;
    ushort_t tmp[16];
    #pragma unroll
    for (int i = 0; i < 16; ++i) tmp[i] = T[ch + i][j];
    ushort_t* o = dst + ((size_t)u * dstCols + colAdd + col0 + j) * 256 + c0 + ch;
    *(bf16x8*)&o[0] = *(const bf16x8*)&tmp[0];
    *(bf16x8*)&o[8] = *(const bf16x8*)&tmp[8];
}

// QKV GEMM, 128x128 tiles, register-double-buffered K-loop.
// Q/K cols -> qkvb row-major; V cols -> ONLY vT (LDS-transposed, coalesced stores).
__global__ __launch_bounds__(256) void k_qkv(
    const ushort_t* __restrict__ X, const ushort_t* __restrict__ WT,
    const float* __restrict__ bv, ushort_t* __restrict__ out,
    ushort_t* __restrict__ vT) {
    __shared__ __align__(16) ushort_t smem[2 * 128 * 72];
    ushort_t (*xs)[72] = (ushort_t (*)[72])smem;
    ushort_t (*wt)[72] = (ushort_t (*)[72])(smem + 128 * 72);
    int col0 = blockIdx.x * 128;
    int row0 = blockIdx.y * 128;
    int u = (row0 >> 9) & 7;
    const ushort_t* Wu = WT + (size_t)(u * 1280 + col0) * 256;
    int tid = threadIdx.x;
    int w = tid >> 6, l = tid & 63;
    int lr = l & 15, lg = l >> 4;
    int wm = w >> 1, wn = w & 1;
    f32x4 acc[4][4] = {};
    int sr = tid >> 3, sko = (tid & 7) * 8;
    bf16x8 xr[4], wr[4];
    #pragma unroll
    for (int it = 0; it < 4; ++it) {
        xr[it] = *(const bf16x8*)&X[(size_t)(row0 + sr + it * 32) * 256 + sko];
        wr[it] = *(const bf16x8*)&Wu[(size_t)(sr + it * 32) * 256 + sko];
    }
    for (int t = 0; t < 4; ++t) {
        #pragma unroll
        for (int it = 0; it < 4; ++it) {
            *(bf16x8*)&xs[sr + it * 32][sko] = xr[it];
            *(bf16x8*)&wt[sr + it * 32][sko] = wr[it];
        }
        __syncthreads();
        if (t < 3) {
            int k0 = (t + 1) * 64;
            #pragma unroll
            for (int it = 0; it < 4; ++it) {
                xr[it] = *(const bf16x8*)&X[(size_t)(row0 + sr + it * 32) * 256 + k0 + sko];
                wr[it] = *(const bf16x8*)&Wu[(size_t)(sr + it * 32) * 256 + k0 + sko];
            }
        }
        #pragma unroll
        for (int m = 0; m < 4; ++m) {
            #pragma unroll
            for (int kk = 0; kk < 2; ++kk) {
                bf16x8 a = *(const bf16x8*)&xs[wm * 64 + m * 16 + lr][kk * 32 + lg * 8];
                #pragma unroll
                for (int n = 0; n < 4; ++n) {
                    bf16x8 bb = *(const bf16x8*)&wt[wn * 64 + n * 16 + lr][kk * 32 + lg * 8];
                    acc[m][n] = __builtin_amdgcn_mfma_f32_16x16x32_bf16(a, bb, acc[m][n], 0, 0, 0);
                }
            }
        }
        __syncthreads();
    }
    if (col0 < 1024) {
        // Q/K path: row-major bf16 stores
        #pragma unroll
        for (int m = 0; m < 4; ++m) {
            int rowb = row0 + wm * 64 + m * 16 + lg * 4;
            #pragma unroll
            for (int n = 0; n < 4; ++n) {
                int col = col0 + wn * 64 + n * 16 + lr;
                #pragma unroll
                for (int i = 0; i < 4; ++i)
                    out[(size_t)(rowb + i) * 1280 + col] = f2bf(acc[m][n][i]);
            }
        }
    } else {
        // V path: bias, transpose via LDS (reuses smem; safe after final barrier),
        // then fully-coalesced vT stores.
        ushort_t (*vbuf)[136] = (ushort_t (*)[136])smem;
        #pragma unroll
        for (int n = 0; n < 4; ++n) {
            int c = wn * 64 + n * 16 + lr;                   // 0..127 local V channel
            float bval = bv[col0 - 1024 + c];
            #pragma unroll
            for (int m = 0; m < 4; ++m) {
                int s = wm * 64 + m * 16 + lg * 4;
                uint2 pw;
                pw.x = cvt_pk_bf16(acc[m][n][0] + bval, acc[m][n][1] + bval);
                pw.y = cvt_pk_bf16(acc[m][n][2] + bval, acc[m][n][3] + bval);
                *(uint2*)&vbuf[c][s] = pw;
            }
        }
        __syncthreads();
        int bu = row0 >> 9;
        size_t grow0 = (size_t)(bu * 256 + (col0 - 1024));
        int srow = row0 & 511;
        int cc = tid >> 4, so = (tid & 15) * 8;
        #pragma unroll
        for (int it = 0; it < 8; ++it) {
            int c = cc + it * 16;
            *(bf16x8*)&vT[(grow0 + c) * 512 + srow + so] = *(const bf16x8*)&vbuf[c][so];
        }
    }
}

// Attention per (bu,h,64-row tile). Swapped QK^T; register prefetch; XCD swizzle;
// cvt_pk P-pack; bf16 att output.
__global__ __launch_bounds__(256) void k_attn(
    const ushort_t* __restrict__ qkv, const ushort_t* __restrict__ vT,
    const float* __restrict__ aff, ushort_t* __restrict__ attB) {
    __shared__ __align__(16) ushort_t Qs[64][72];
    __shared__ __align__(16) ushort_t Ks[64][72];
    __shared__ __align__(16) ushort_t Pt[64][72];
    __shared__ __align__(16) ushort_t Vt[32][72];
    __shared__ float As[64];
    int id = blockIdx.x;
    int xcd = id & 7, sl = id >> 3;
    int bu = xcd + 8 * (sl >> 6);
    int inr = sl & 63;
    int h = inr & 7;
    int r0 = (inr >> 3) * 64;
    const ushort_t* base = qkv + (size_t)bu * 512 * 1280;
    const ushort_t* vbase = vT + (size_t)((bu * 8 + h) * 32) * 512;
    int tid = threadIdx.x;
    int w = tid >> 6, l = tid & 63;
    int lr = l & 15, lg = l >> 4;
    int sr = tid >> 3, sko = (tid & 7) * 8;
    *(bf16x8*)&Qs[sr][sko]      = *(const bf16x8*)&base[(size_t)(r0 + sr) * 1280 + h * 64 + sko];
    *(bf16x8*)&Qs[sr + 32][sko] = *(const bf16x8*)&base[(size_t)(r0 + sr + 32) * 1280 + h * 64 + sko];
    bf16x8 kr0 = *(const bf16x8*)&base[(size_t)sr * 1280 + 512 + h * 64 + sko];
    bf16x8 kr1 = *(const bf16x8*)&base[(size_t)(sr + 32) * 1280 + 512 + h * 64 + sko];
    bf16x8 vr  = *(const bf16x8*)&vbase[(size_t)sr * 512 + sko];
    float afv = (tid < 64) ? aff[bu * 512 + tid] : 0.f;
    *(bf16x8*)&Ks[sr][sko] = kr0;
    *(bf16x8*)&Ks[sr + 32][sko] = kr1;
    if (sr < 32) *(bf16x8*)&Vt[sr][sko] = vr;
    if (tid < 64) As[tid] = afv;
    __syncthreads();
    float wsum = 0.f, asum = 0.f;
    f32x4 pacc[2] = {};
    for (int t = 0; t < 8; ++t) {
        int s0n = (t + 1) * 64;
        if (t < 7) {
            kr0 = *(const bf16x8*)&base[(size_t)(s0n + sr) * 1280 + 512 + h * 64 + sko];
            kr1 = *(const bf16x8*)&base[(size_t)(s0n + sr + 32) * 1280 + 512 + h * 64 + sko];
            if (sr < 32) vr = *(const bf16x8*)&vbase[(size_t)sr * 512 + s0n + sko];
            if (tid < 64) afv = aff[bu * 512 + s0n + tid];
        }
        #pragma unroll
        for (int n = 0; n < 4; ++n) {
            f32x4 sc = {};
            #pragma unroll
            for (int kk = 0; kk < 2; ++kk) {
                bf16x8 ka = *(const bf16x8*)&Ks[n * 16 + lr][kk * 32 + lg * 8];
                bf16x8 qb = *(const bf16x8*)&Qs[w * 16 + lr][kk * 32 + lg * 8];
                sc = __builtin_amdgcn_mfma_f32_16x16x32_bf16(ka, qb, sc, 0, 0, 0);
            }
            float4 a4 = *(const float4*)&As[n * 16 + lg * 4];
            float e0 = __expf(sc[0]), e1 = __expf(sc[1]);
            float e2 = __expf(sc[2]), e3 = __expf(sc[3]);
            wsum += (e0 + e1) + (e2 + e3);
            float ae0 = e0 * a4.x, ae1 = e1 * a4.y, ae2 = e2 * a4.z, ae3 = e3 * a4.w;
            asum += (ae0 + ae1) + (ae2 + ae3);
            uint2 pw;
            pw.x = cvt_pk_bf16(ae0, ae1);
            pw.y = cvt_pk_bf16(ae2, ae3);
            *(uint2*)&Pt[w * 16 + lr][n * 16 + lg * 4] = pw;
        }
        #pragma unroll
        for (int n = 0; n < 2; ++n) {
            #pragma unroll
            for (int kk = 0; kk < 2; ++kk) {
                bf16x8 pa = *(const bf16x8*)&Pt[w * 16 + lr][kk * 32 + lg * 8];
                bf16x8 vb = *(const bf16x8*)&Vt[n * 16 + lr][kk * 32 + lg * 8];
                pacc[n] = __builtin_amdgcn_mfma_f32_16x16x32_bf16(pa, vb, pacc[n], 0, 0, 0);
            }
        }
        __syncthreads();
        if (t < 7) {
            *(bf16x8*)&Ks[sr][sko] = kr0;
            *(bf16x8*)&Ks[sr + 32][sko] = kr1;
            if (sr < 32) *(bf16x8*)&Vt[sr][sko] = vr;
            if (tid < 64) As[tid] = afv;
            __syncthreads();
        }
    }
    asum += __shfl_xor(asum, 16); asum += __shfl_xor(asum, 32);
    wsum += __shfl_xor(wsum, 16); wsum += __shfl_xor(wsum, 32);
    float ar = aff[bu * 512 + r0 + w * 16 + lr];
    float scale = ar / (ar * asum + EPS_ * wsum);
    #pragma unroll
    for (int i = 0; i < 4; ++i) {
        float sc_i = __shfl(scale, lg * 4 + i);
        int q = r0 + w * 16 + lg * 4 + i;
        ushort_t* ob = attB + ((size_t)bu * 512 + q) * 256 + h * 32;
        ob[lr]      = f2bf(pacc[0][i] * sc_i);
        ob[16 + lr] = f2bf(pacc[1][i] * sc_i);
    }
}

// Fused tail, 16 rows/block (512 blocks, 2/CU): gate+LN2 -> yn (LDS), ao cached in
// LDS (f32); MLP1+gelu -> yn (LDS); MLP2+gelu + final gating from aoL -> out.
__global__ __launch_bounds__(256) void k_tail(
    const float* __restrict__ x, const ushort_t* __restrict__ attB,
    const float* __restrict__ aff, const float* __restrict__ g2,
    const float* __restrict__ b2, const ushort_t* __restrict__ w1T,
    const ushort_t* __restrict__ w2T, const float* __restrict__ b1m,
    const float* __restrict__ b2m, float* __restrict__ outp) {
    __shared__ __align__(16) ushort_t ynL[16][264];
    __shared__ __align__(16) float aoL[16][260];
    __shared__ __align__(16) ushort_t wt[256][72];
    int r0 = blockIdx.x * 16;
    int u = (r0 >> 9) & 7;
    int tid = threadIdx.x;
    // ---- phase 1: gate + LN2; ao -> aoL (f32), yn -> ynL (bf16) ----
    {
        int row = tid >> 4, cb = (tid & 15) * 16;
        float a = aff[r0 + row];
        const float* xr = x + (size_t)(r0 + row) * 256 + cb;
        const ushort_t* ar = attB + (size_t)(r0 + row) * 256 + cb;
        ushort_t av[16];
        *(bf16x8*)&av[0] = *(const bf16x8*)&ar[0];
        *(bf16x8*)&av[8] = *(const bf16x8*)&ar[8];
        float o[16];
        float s = 0.f, ss = 0.f;
        #pragma unroll
        for (int j = 0; j < 16; ++j) {
            float t = (1.f - a) * xr[j] + a * GAIN_ * bf2f(av[j]);
            o[j] = t; s += t; ss += t * t;
        }
        s += __shfl_xor(s, 1); s += __shfl_xor(s, 2);
        s += __shfl_xor(s, 4); s += __shfl_xor(s, 8);
        ss += __shfl_xor(ss, 1); ss += __shfl_xor(ss, 2);
        ss += __shfl_xor(ss, 4); ss += __shfl_xor(ss, 8);
        float mean = s * (1.f / 256.f);
        float var = ss * (1.f / 256.f) - mean * mean;
        float rstd = rsqrtf(var + LN_EPS_);
        #pragma unroll
        for (int j = 0; j < 16; j += 4) {
            float4 gg = *(const float4*)&g2[cb + j];
            float4 bb = *(const float4*)&b2[cb + j];
            *(float4*)&aoL[row][cb + j] = make_float4(o[j], o[j+1], o[j+2], o[j+3]);
            uint2 pk;
            pk.x = cvt_pk_bf16((o[j]   - mean) * rstd * gg.x + bb.x,
                               (o[j+1] - mean) * rstd * gg.y + bb.y);
            pk.y = cvt_pk_bf16((o[j+2] - mean) * rstd * gg.z + bb.z,
                               (o[j+3] - mean) * rstd * gg.w + bb.w);
            *(uint2*)&ynL[row][cb + j] = pk;
        }
    }
    __syncthreads();
    int w = tid >> 6, l = tid & 63, lr = l & 15, lg = l >> 4;
    int scol = tid >> 3, sko = (tid & 7) * 8;
    const ushort_t* W1u = w1T + (size_t)u * 65536;
    const ushort_t* W2u = w2T + (size_t)u * 65536;
    // ---- MLP1 (transposed: A = W1^T rows = out-channels, B = yn rows = tokens) ----
    f32x4 acc[4] = {};
    for (int k0 = 0; k0 < 256; k0 += 64) {
        #pragma unroll
        for (int it = 0; it < 8; ++it)
            *(bf16x8*)&wt[scol + it * 32][sko] =
                *(const bf16x8*)&W1u[(size_t)(scol + it * 32) * 256 + k0 + sko];
        __syncthreads();
        #pragma unroll
        for (int n = 0; n < 4; ++n) {
            #pragma unroll
            for (int kk = 0; kk < 2; ++kk) {
                bf16x8 a = *(const bf16x8*)&wt[w * 64 + n * 16 + lr][kk * 32 + lg * 8];
                bf16x8 b = *(const bf16x8*)&ynL[lr][k0 + kk * 32 + lg * 8];
                acc[n] = __builtin_amdgcn_mfma_f32_16x16x32_bf16(a, b, acc[n], 0, 0, 0);
            }
        }
        __syncthreads();
    }
    // h1 = gelu(out1 + b1) -> ynL (disjoint per-wave column ranges)
    #pragma unroll
    for (int n = 0; n < 4; ++n) {
        int nc = w * 64 + n * 16 + lg * 4;
        float4 bv1 = *(const float4*)&b1m[nc];
        uint2 pw;
        pw.x = cvt_pk_bf16(gelu_exact(acc[n][0] + bv1.x), gelu_exact(acc[n][1] + bv1.y));
        pw.y = cvt_pk_bf16(gelu_exact(acc[n][2] + bv1.z), gelu_exact(acc[n][3] + bv1.w));
        *(uint2*)&ynL[lr][nc] = pw;
    }
    __syncthreads();
    // ---- MLP2 (transposed) ----
    f32x4 acc2[4] = {};
    for (int k0 = 0; k0 < 256; k0 += 64) {
        #pragma unroll
        for (int it = 0; it < 8; ++it)
            *(bf16x8*)&wt[scol + it * 32][sko] =
                *(const bf16x8*)&W2u[(size_t)(scol + it * 32) * 256 + k0 + sko];
        __syncthreads();
        #pragma unroll
        for (int n = 0; n < 4; ++n) {
            #pragma unroll
            for (int kk = 0; kk < 2; ++kk) {
                bf16x8 a = *(const bf16x8*)&wt[w * 64 + n * 16 + lr][kk * 32 + lg * 8];
                bf16x8 b = *(const bf16x8*)&ynL[lr][k0 + kk * 32 + lg * 8];
                acc2[n] = __builtin_amdgcn_mfma_f32_16x16x32_bf16(a, b, acc2[n], 0, 0, 0);
            }
        }
        __syncthreads();
    }
    // ---- epilogue: gelu + final gating from aoL ----
    int orow = r0 + lr;
    float a = aff[orow];
    #pragma unroll
    for (int n = 0; n < 4; ++n) {
        int nc = w * 64 + n * 16 + lg * 4;
        float4 bv2 = *(const float4*)&b2m[nc];
        float4 r;
        {
            float h2 = gelu_exact(acc2[n][0] + bv2.x);
            r.x = (1.f - a) * aoL[lr][nc + 0] + GAIN_ * a * a * h2;
        }
        {
            float h2 = gelu_exact(acc2[n][1] + bv2.y);
            r.y = (1.f - a) * aoL[lr][nc + 1] + GAIN_ * a * a * h2;
        }
        {
            float h2 = gelu_exact(acc2[n][2] + bv2.z);
            r.z = (1.f - a) * aoL[lr][nc + 2] + GAIN_ * a * a * h2;
        }
        {
            float h2 = gelu_exact(acc2[n][3] + bv2.w);
            r.w = (1.f - a) * aoL[lr][nc + 3] + GAIN_ * a * a * h2;
        }
        *(float4*)&outp[(size_t)orow * 256 + nc] = r;
    }
}

extern "C" void kernel_launch(void* const* d_in, const int* in_sizes, int n_in,
                              void* d_out, int out_size, void* d_ws, size_t ws_size,
                              hipStream_t stream) {
    const float* variables  = (const float*)d_in[0];
    const float* codes      = (const float*)d_in[1];
    const float* affinities = (const float*)d_in[2];
    const float* ln1_g = (const float*)d_in[3];
    const float* ln1_b = (const float*)d_in[4];
    const float* Wq  = (const float*)d_in[5];
    const float* Wcq = (const float*)d_in[6];
    const float* Wk  = (const float*)d_in[7];
    const float* Wck = (const float*)d_in[8];
    const float* Wv  = (const float*)d_in[9];
    const float* Wcv = (const float*)d_in[10];
    const float* bv  = (const float*)d_in[11];
    const float* ln2_g = (const float*)d_in[12];
    const float* ln2_b = (const float*)d_in[13];
    const float* W1  = (const float*)d_in[14];
    const float* Wc1 = (const float*)d_in[15];
    const float* b1m = (const float*)d_in[16];
    const float* W2  = (const float*)d_in[17];
    const float* Wc2 = (const float*)d_in[18];
    const float* b2m = (const float*)d_in[19];

    char* p = (char*)d_ws;
    ushort_t* attB  = (ushort_t*)p; p += 4194304;   // [8192][256] bf16
    ushort_t* xnb   = (ushort_t*)p; p += 4194304;   // [8192][256] bf16
    ushort_t* wqkvT = (ushort_t*)p; p += 5242880;   // [8][1280][256] bf16
    ushort_t* w1T   = (ushort_t*)p; p += 1048576;   // [8][256][256] bf16
    ushort_t* w2T   = (ushort_t*)p; p += 1048576;   // [8][256][256] bf16
    ushort_t* qkvb  = (ushort_t*)p; p += 20971520;  // [8192][1280] bf16 (V cols unused)
    ushort_t* vTb   = (ushort_t*)p; p += 4194304;   // [16*8][32][512] bf16
    float* outp = (float*)d_out;

    k_prep<<<2944, 256, 0, stream>>>(codes, Wcq, Wck, Wcv, Wc1, Wc2,
                                     Wq, Wk, Wv, W1, W2,
                                     variables, ln1_g, ln1_b,
                                     wqkvT, w1T, w2T, xnb);
    k_qkv<<<dim3(10, 64), 256, 0, stream>>>(xnb, wqkvT, bv, qkvb, vTb);
    k_attn<<<1024, 256, 0, stream>>>(qkvb, vTb, affinities, attB);
    k_tail<<<512, 256, 0, stream>>>(variables, attB, affinities, ln2_g, ln2_b,
                                    w1T, w2T, b1m, b2m, outp);
}